// Round 1
// baseline (280.570 us; speedup 1.0000x reference)
//
#include <hip/hip_runtime.h>
#include <math.h>

#define NN 100000
#define CC 128
#define KK 32
#define BG 16
#define EPSF 1e-9f

// d_out float layout: out[16][32][128] | s[100000][32] | mu[16][32][2] | losses[9]
#define S_OFF 65536
#define MU_OFF 3265536
#define LOSS_OFF 3266560

// ws float layout
#define WS_ENT 0
#define WS_SB_S 16
#define WS_SB_PX 528
#define WS_SB_PY 1040
#define WS_SB_SQ 1552
#define WS_TOTAL 2064

// ---------------- kernel 1: MLP + gumbel softmax + stats ----------------
// block = 256 threads (4 waves), 64 nodes per block.
// phase1: wave w computes h[node=lane][j in w*32..w*32+32], W1 via scalar loads
// phase2: wave w computes logits[node=lane][k in w*8..w*8+8], W2 scalar
// softmax: thread (n=t>>2, q=t&3) owns 8 k's
// stats: thread (k=t&31, chunk=t>>5) runs 8 nodes, per-b running sums -> global atomics
__global__ __launch_bounds__(256) void k_assign(
    const float* __restrict__ x, const int* __restrict__ batch,
    const float* __restrict__ pos, const float* __restrict__ gum,
    const float* __restrict__ W1, const float* __restrict__ b1,
    const float* __restrict__ W2, const float* __restrict__ b2,
    const float* __restrict__ scaling, const float* __restrict__ amask,
    float* __restrict__ dout, float* __restrict__ ws)
{
    __shared__ float xs[64][129];   // x tile, later reused for h (pad 129 -> conflict-free col reads)
    __shared__ float llds[64][33];  // logits, later s
    __shared__ float lpx[64], lpy[64], lpsq[64];
    __shared__ int lbat[64];
    __shared__ float s_ent;

    const int t = threadIdx.x;
    const int n0 = blockIdx.x * 64;

    // stage x tile (coalesced float4 reads)
    {
        const int cc4 = (t & 31) * 4;
        const int nb = t >> 5;
#pragma unroll
        for (int r = 0; r < 8; ++r) {
            int n = r * 8 + nb;
            int gn = n0 + n;
            float4 v = make_float4(0.f, 0.f, 0.f, 0.f);
            if (gn < NN) v = *(const float4*)(x + gn * CC + cc4);
            xs[n][cc4] = v.x; xs[n][cc4 + 1] = v.y; xs[n][cc4 + 2] = v.z; xs[n][cc4 + 3] = v.w;
        }
    }
    if (t < 64) {
        int gn = n0 + t;
        float px = 0.f, py = 0.f; int bb = 0;
        if (gn < NN) { px = pos[gn * 2]; py = pos[gn * 2 + 1]; bb = batch[gn]; }
        lpx[t] = px; lpy[t] = py; lpsq[t] = px * px + py * py; lbat[t] = bb;
    }
    if (t == 0) s_ent = 0.f;
    __syncthreads();

    const int lane = t & 63;
    const int wv = __builtin_amdgcn_readfirstlane(t >> 6);

    // ---- phase 1: h = relu(x @ W1 + b1), wave handles 32 j's for all 64 nodes
    float h[32];
#pragma unroll
    for (int j = 0; j < 32; ++j) h[j] = 0.f;
    const float* w1p = W1 + wv * 32;
#pragma unroll 4
    for (int c = 0; c < CC; ++c) {
        float xv = xs[lane][c];
        const float* wr = w1p + c * CC;   // wave-uniform -> s_load
#pragma unroll
        for (int j = 0; j < 32; ++j) h[j] = fmaf(xv, wr[j], h[j]);
    }
    {
        const float* b1p = b1 + wv * 32;
#pragma unroll
        for (int j = 0; j < 32; ++j) h[j] = fmaxf(h[j] + b1p[j], 0.f);
    }
    __syncthreads();            // all xs reads done
#pragma unroll
    for (int j = 0; j < 32; ++j) xs[lane][wv * 32 + j] = h[j];
    __syncthreads();

    // ---- phase 2: logits = (h @ W2 + b2) * scaling, wave handles 8 k's
    float lg[8];
#pragma unroll
    for (int i = 0; i < 8; ++i) lg[i] = 0.f;
    const float* w2p = W2 + wv * 8;
#pragma unroll 4
    for (int j = 0; j < CC; ++j) {
        float hv = xs[lane][j];
        const float* wr = w2p + j * KK;   // wave-uniform -> s_load
#pragma unroll
        for (int i = 0; i < 8; ++i) lg[i] = fmaf(hv, wr[i], lg[i]);
    }
    {
        const float sc = scaling[0];
#pragma unroll
        for (int i = 0; i < 8; ++i) {
            int k = wv * 8 + i;
            float v = (lg[i] + b2[k]) * sc;
            if (amask[k] == 0.f) v = -1e9f;
            llds[lane][k] = v;
        }
    }
    __syncthreads();

    // ---- softmax + entropy; thread (n,q) owns k = q*8..q*8+8
    {
        const int n = t >> 2, q = t & 3;
        const int gn = n0 + n;
        const bool valid = gn < NN;
        float z[8];
        float m = -1e30f;
        const float* gp = gum + (size_t)gn * KK + q * 8;
#pragma unroll
        for (int i = 0; i < 8; ++i) {
            float u = valid ? gp[i] : 0.5f;
            float g = -logf(-logf(u + EPSF) + EPSF);
            z[i] = llds[n][q * 8 + i] + g;   // TAU = 1
            m = fmaxf(m, z[i]);
        }
        m = fmaxf(m, __shfl_xor(m, 1));
        m = fmaxf(m, __shfl_xor(m, 2));
        float ssum = 0.f;
#pragma unroll
        for (int i = 0; i < 8; ++i) { z[i] = expf(z[i] - m); ssum += z[i]; }
        ssum += __shfl_xor(ssum, 1);
        ssum += __shfl_xor(ssum, 2);
        const float inv = 1.f / ssum;
        float ep = 0.f;
#pragma unroll
        for (int i = 0; i < 8; ++i) {
            float sv = z[i] * inv;
            z[i] = sv;
            ep += sv * logf(sv + EPSF);
        }
        if (valid) {
            float4 o0 = make_float4(z[0], z[1], z[2], z[3]);
            float4 o1 = make_float4(z[4], z[5], z[6], z[7]);
            *(float4*)(dout + S_OFF + (size_t)gn * KK + q * 8) = o0;
            *(float4*)(dout + S_OFF + (size_t)gn * KK + q * 8 + 4) = o1;
        }
#pragma unroll
        for (int i = 0; i < 8; ++i) llds[n][q * 8 + i] = z[i];
        if (!valid) ep = 0.f;
        ep += __shfl_xor(ep, 1);
        ep += __shfl_xor(ep, 2);
        float ep2 = (q == 0) ? ep : 0.f;
        ep2 += __shfl_down(ep2, 32);
        ep2 += __shfl_down(ep2, 16);
        ep2 += __shfl_down(ep2, 8);
        ep2 += __shfl_down(ep2, 4);
        if (lane == 0) atomicAdd(&s_ent, ep2);
    }
    __syncthreads();

    // ---- stats: per-(b,k) running sums (nodes sorted by b)
    {
        const int k = t & 31, ch = t >> 5;
        float rs = 0.f, rpx = 0.f, rpy = 0.f, rsq = 0.f;
        int cur_b = -1;
        for (int r = 0; r < 8; ++r) {
            int n = ch * 8 + r;
            int gn = n0 + n;
            if (gn < NN) {
                int bb = lbat[n];
                if (bb != cur_b) {
                    if (cur_b >= 0) {
                        atomicAdd(ws + WS_SB_S  + cur_b * KK + k, rs);
                        atomicAdd(ws + WS_SB_PX + cur_b * KK + k, rpx);
                        atomicAdd(ws + WS_SB_PY + cur_b * KK + k, rpy);
                        atomicAdd(ws + WS_SB_SQ + cur_b * KK + k, rsq);
                    }
                    cur_b = bb; rs = rpx = rpy = rsq = 0.f;
                }
                float sv = llds[n][k];
                rs += sv; rpx += sv * lpx[n]; rpy += sv * lpy[n]; rsq += sv * lpsq[n];
            }
        }
        if (cur_b >= 0) {
            atomicAdd(ws + WS_SB_S  + cur_b * KK + k, rs);
            atomicAdd(ws + WS_SB_PX + cur_b * KK + k, rpx);
            atomicAdd(ws + WS_SB_PY + cur_b * KK + k, rpy);
            atomicAdd(ws + WS_SB_SQ + cur_b * KK + k, rsq);
        }
    }
    if (t == 0) atomicAdd(ws + WS_ENT, s_ent);
}

// ---------------- kernel 2: pooling out[b,k,c] = sum s[i,k]*x[i,c] ----------------
// block = 256 threads; 128 nodes per block; thread owns column c=t&127, acc[32] over k.
// s rows are wave-uniform -> SGPR scalar loads. Flush via atomics on graph change / end.
__global__ __launch_bounds__(256) void k_pool(
    const float* __restrict__ x, const int* __restrict__ batch,
    const float* __restrict__ s, float* __restrict__ out)
{
    __shared__ float lx[8][128];
    __shared__ int lb[8];
    const int t = threadIdx.x;
    const int c = t & 127;
    const int sub = __builtin_amdgcn_readfirstlane(t >> 7);
    const int i0 = blockIdx.x * 128;
    float acc[32];
#pragma unroll
    for (int k = 0; k < 32; ++k) acc[k] = 0.f;
    int cur_b = -1;

    for (int g = 0; g < 16; ++g) {
        const int base = i0 + g * 8;
        __syncthreads();
        {
            int j = t >> 5;
            int cc4 = (t & 31) * 4;
            int gn = base + j;
            float4 v = make_float4(0.f, 0.f, 0.f, 0.f);
            if (gn < NN) v = *(const float4*)(x + (size_t)gn * CC + cc4);
            *(float4*)(&lx[j][cc4]) = v;
        }
        if (t < 8) lb[t] = (base + t < NN) ? batch[base + t] : -1;
        __syncthreads();
        for (int j = 0; j < 8; ++j) {
            int gn = base + j;
            if (gn >= NN) break;                 // uniform
            int bb = lb[j];
            if (bb != cur_b) {                   // uniform
                if (cur_b >= 0) {
                    int baseo = cur_b * (KK * CC) + c;
#pragma unroll
                    for (int k = 0; k < 32; ++k) { atomicAdd(out + baseo + k * CC, acc[k]); acc[k] = 0.f; }
                }
                cur_b = bb;
            }
            if ((j & 1) == sub) {                // wave-uniform split of nodes
                float xv = lx[j][c];
                const float* srow = s + (size_t)gn * KK;   // uniform -> s_load
#pragma unroll
                for (int k = 0; k < 32; ++k) acc[k] = fmaf(xv, srow[k], acc[k]);
            }
        }
    }
    if (cur_b >= 0) {
        int baseo = cur_b * (KK * CC) + c;
#pragma unroll
        for (int k = 0; k < 32; ++k) atomicAdd(out + baseo + k * CC, acc[k]);
    }
}

// ---------------- kernel 3: finalize losses + centroids ----------------
__global__ __launch_bounds__(256) void k_final(
    const float* __restrict__ ws, const float* __restrict__ amask,
    float* __restrict__ dout)
{
    __shared__ float avg[32], csum[32], cpx[32], cpy[32], csq[32];
    __shared__ float lmu[16][32][2];
    __shared__ float red[4];
    const int t = threadIdx.x;
    if (t < 32) {
        float a = 0.f, px = 0.f, py = 0.f, sq = 0.f;
        for (int b = 0; b < BG; ++b) {
            a  += ws[WS_SB_S  + b * KK + t];
            px += ws[WS_SB_PX + b * KK + t];
            py += ws[WS_SB_PY + b * KK + t];
            sq += ws[WS_SB_SQ + b * KK + t];
        }
        csum[t] = a; cpx[t] = px; cpy[t] = py; csq[t] = sq;
        avg[t] = a / (float)NN;
    }
    for (int idx = t; idx < BG * KK; idx += 256) {
        float den = ws[WS_SB_S + idx] + EPSF;
        float mx = ws[WS_SB_PX + idx] / den;
        float my = ws[WS_SB_PY + idx] / den;
        int b = idx >> 5, k = idx & 31;
        lmu[b][k][0] = mx; lmu[b][k][1] = my;
        dout[MU_OFF + idx * 2] = mx;
        dout[MU_OFF + idx * 2 + 1] = my;
    }
    __syncthreads();
    float sep = 0.f;
    for (int idx = t; idx < BG * KK * KK; idx += 256) {
        int b = idx >> 10, k1 = (idx >> 5) & 31, k2 = idx & 31;
        if (k1 != k2) {
            float dx = lmu[b][k1][0] - lmu[b][k2][0];
            float dy = lmu[b][k1][1] - lmu[b][k2][1];
            sep += 1.f / (dx * dx + dy * dy + 1.f);
        }
    }
    for (int off = 32; off; off >>= 1) sep += __shfl_down(sep, off);
    if ((t & 63) == 0) red[t >> 6] = sep;
    __syncthreads();
    if (t == 0) {
        float sept = red[0] + red[1] + red[2] + red[3];
        float separation = sept / ((float)(KK * (KK - 1)) + EPSF);
        float entropy = -ws[WS_ENT] / (float)NN;
        float diversity = 0.f, pruning = 0.f, msum = 0.f, entavg = 0.f, bal = 0.f, mxa = 0.f, spatial = 0.f;
        const float up = 1.f / (float)KK;
        for (int k = 0; k < KK; ++k) {
            float a = avg[k];
            diversity += up * logf(up / (a + EPSF));
            float mk = amask[k];
            pruning += fabsf(a * (1.f - mk));
            msum += mk;
            entavg -= a * logf(a + EPSF);
            bal += a * logf(a * (float)KK + EPSF);
            mxa = fmaxf(mxa, a);
            float den = csum[k] + EPSF;
            float mux = cpx[k] / den, muy = cpy[k] / den;
            spatial += csq[k] / den - (mux * mux + muy * muy);
        }
        pruning *= up;
        spatial *= up;
        const float lk = logf((float)KK);
        float collapse = ((lk - entavg) / lk + fmaxf(mxa - 2.f / (float)KK, 0.f)) * 2.0f;
        float sparsity = (msum / (float)KK) * 0.01f;
        dout[LOSS_OFF + 0] = entropy;
        dout[LOSS_OFF + 1] = diversity;
        dout[LOSS_OFF + 2] = spatial;
        dout[LOSS_OFF + 3] = pruning;
        dout[LOSS_OFF + 4] = sparsity;
        dout[LOSS_OFF + 5] = 0.f;
        dout[LOSS_OFF + 6] = collapse;
        dout[LOSS_OFF + 7] = bal;
        dout[LOSS_OFF + 8] = separation;
    }
}

extern "C" void kernel_launch(void* const* d_in, const int* in_sizes, int n_in,
                              void* d_out, int out_size, void* d_ws, size_t ws_size,
                              hipStream_t stream) {
    const float* x     = (const float*)d_in[0];
    const int*   batch = (const int*)d_in[1];
    const float* pos   = (const float*)d_in[2];
    const float* gum   = (const float*)d_in[3];
    const float* W1    = (const float*)d_in[4];
    const float* b1    = (const float*)d_in[5];
    const float* W2    = (const float*)d_in[6];
    const float* b2    = (const float*)d_in[7];
    const float* scal  = (const float*)d_in[8];
    const float* amask = (const float*)d_in[9];
    float* dout = (float*)d_out;
    float* ws   = (float*)d_ws;

    hipMemsetAsync(dout, 0, S_OFF * sizeof(float), stream);         // out region only
    hipMemsetAsync(ws, 0, WS_TOTAL * sizeof(float), stream);

    k_assign<<<(NN + 63) / 64, 256, 0, stream>>>(x, batch, pos, gum, W1, b1, W2, b2,
                                                 scal, amask, dout, ws);
    k_pool<<<(NN + 127) / 128, 256, 0, stream>>>(x, batch, dout + S_OFF, dout);
    k_final<<<1, 256, 0, stream>>>(ws, amask, dout);
}

// Round 2
// 211.069 us; speedup vs baseline: 1.3293x; 1.3293x over previous
//
#include <hip/hip_runtime.h>
#include <math.h>

#define NN 100000
#define CC 128
#define KK 32
#define BG 16
#define EPSF 1e-9f

// d_out float layout: out[16][32][128] | s[100000][32] | mu[16][32][2] | losses[9]
#define S_OFF 65536
#define MU_OFF 3265536
#define LOSS_OFF 3266560

// ws float layout (stats), then W fragment buffers at byte offsets
#define WS_ENT 0
#define WS_SB_S 16
#define WS_SB_PX 528
#define WS_SB_PY 1040
#define WS_SB_SQ 1552
#define WS_TOTAL 2064

#define W1B_OFF_BYTES 16384
#define W2B_OFF_BYTES (16384 + 65536)

typedef __attribute__((ext_vector_type(8))) short short8v;
typedef __attribute__((ext_vector_type(4))) short short4v;
typedef __attribute__((ext_vector_type(4))) float float4v;

#define MFMA16(a, b, c) __builtin_amdgcn_mfma_f32_16x16x32_bf16((a), (b), (c), 0, 0, 0)

__device__ __forceinline__ short f2bf(float f) {
    unsigned u = __float_as_uint(f);
    unsigned r = (u + 0x7fffu + ((u >> 16) & 1u)) >> 16;
    return (short)r;
}
__device__ __forceinline__ float bf2f(short s) {
    return __uint_as_float(((unsigned)(unsigned short)s) << 16);
}

// ---------------- prep: split W1/W2 to bf16 hi/lo in B-fragment layout ----------------
// B[k][n] fragment for mfma_16x16x32: lane l reads k = ks*32 + (l>>4)*8 + j, n = nt*16 + (l&15)
// storage: [nt][ks][hl][lane][j] shorts -> coalesced dwordx4 per (nt,ks,hl)
__global__ __launch_bounds__(256) void k_prep(const float* __restrict__ W1,
                                              const float* __restrict__ W2,
                                              short* __restrict__ wW1,
                                              short* __restrict__ wW2) {
    int tid = blockIdx.x * 256 + threadIdx.x;
    if (tid < 8 * 4 * 64) {                       // W1: nt(8), ks(4), lane(64)
        int l = tid & 63, ks = (tid >> 6) & 3, nt = tid >> 8;
        int n = nt * 16 + (l & 15);
        int cb = ks * 32 + (l >> 4) * 8;
        short8v H, L;
#pragma unroll
        for (int j = 0; j < 8; ++j) {
            float v = W1[(size_t)(cb + j) * CC + n];
            short hh = f2bf(v);
            H[j] = hh;
            L[j] = f2bf(v - bf2f(hh));
        }
        ((short8v*)wW1)[((nt * 4 + ks) * 2 + 0) * 64 + l] = H;
        ((short8v*)wW1)[((nt * 4 + ks) * 2 + 1) * 64 + l] = L;
    } else if (tid < 2048 + 512) {                // W2: nt(2), ks(4), lane(64)
        int t2 = tid - 2048;
        int l = t2 & 63, ks = (t2 >> 6) & 3, nt = t2 >> 8;
        int n = nt * 16 + (l & 15);
        int cb = ks * 32 + (l >> 4) * 8;
        short8v H, L;
#pragma unroll
        for (int j = 0; j < 8; ++j) {
            float v = W2[(size_t)(cb + j) * KK + n];
            short hh = f2bf(v);
            H[j] = hh;
            L[j] = f2bf(v - bf2f(hh));
        }
        ((short8v*)wW2)[((nt * 4 + ks) * 2 + 0) * 64 + l] = H;
        ((short8v*)wW2)[((nt * 4 + ks) * 2 + 1) * 64 + l] = L;
    }
}

// ---------------- fused: MLP (MFMA) + gumbel softmax + stats + pooling ----------------
// 64 nodes/block, 256 threads (4 waves).
__global__ __launch_bounds__(256) void k_assign(
    const float* __restrict__ x, const int* __restrict__ batch,
    const float* __restrict__ pos, const float* __restrict__ gum,
    const float* __restrict__ b1, const float* __restrict__ b2,
    const float* __restrict__ scaling, const float* __restrict__ amask,
    const short* __restrict__ wW1, const short* __restrict__ wW2,
    float* __restrict__ dout, float* __restrict__ ws)
{
    __shared__ short xh[64][136];   // x hi (later h hi); 136*2=272B row = 17*16 (b128-aligned)
    __shared__ short xl[64][136];   // x lo (later h lo)
    __shared__ short xt[128][72];   // x^T hi only (pooling B); 144B row = 9*16
    __shared__ short st[32][72];    // s^T bf16 (pooling A + stats)
    __shared__ float lpx[64], lpy[64], lpsq[64];
    __shared__ int lbat[64];
    __shared__ float s_ent;

    const int t = threadIdx.x;
    const int n0 = blockIdx.x * 64;

    // ---- stage x -> split bf16 LDS (coalesced float4) ----
    {
        const int cc4 = (t & 31) * 4;
        const int nb = t >> 5;
#pragma unroll
        for (int r = 0; r < 8; ++r) {
            int n = r * 8 + nb;
            int gn = n0 + n;
            float4 v = make_float4(0.f, 0.f, 0.f, 0.f);
            if (gn < NN) v = *(const float4*)(x + (size_t)gn * CC + cc4);
            short h0 = f2bf(v.x), h1 = f2bf(v.y), h2 = f2bf(v.z), h3 = f2bf(v.w);
            short l0 = f2bf(v.x - bf2f(h0)), l1 = f2bf(v.y - bf2f(h1));
            short l2 = f2bf(v.z - bf2f(h2)), l3 = f2bf(v.w - bf2f(h3));
            *(short4v*)&xh[n][cc4] = (short4v){h0, h1, h2, h3};
            *(short4v*)&xl[n][cc4] = (short4v){l0, l1, l2, l3};
        }
    }
    if (t < 64) {
        int gn = n0 + t;
        float px = 0.f, py = 0.f; int bb = 0;
        if (gn < NN) { px = pos[gn * 2]; py = pos[gn * 2 + 1]; bb = batch[gn]; }
        lpx[t] = px; lpy[t] = py; lpsq[t] = px * px + py * py; lbat[t] = bb;
    }
    if (t == 0) s_ent = 0.f;
    __syncthreads();   // S1

    const int l = t & 63;
    const int wv = __builtin_amdgcn_readfirstlane(t >> 6);
    const int li = l & 15;
    const int g16 = l >> 4;

    // ---- transpose hi(x) into xt[c][i] (for pooling B operand) ----
    {
        const int c = t >> 1, hf = t & 1;
#pragma unroll
        for (int j = 0; j < 32; ++j) {
            int i = hf * 32 + j;
            xt[c][i] = xh[i][c];
        }
    }

    // ---- GEMM1: h = x @ W1, split-bf16 3-term MFMA.
    // wave w owns n-cols [32w,32w+32) (2 n-tiles), all 4 m-tiles.
    float4v acc[4][2];
#pragma unroll
    for (int mt = 0; mt < 4; ++mt) {
        acc[mt][0] = (float4v){0.f, 0.f, 0.f, 0.f};
        acc[mt][1] = (float4v){0.f, 0.f, 0.f, 0.f};
    }
    const short8v* W1B = (const short8v*)wW1;
#pragma unroll
    for (int ks = 0; ks < 4; ++ks) {
        short8v bh0 = W1B[(((2 * wv    ) * 4 + ks) * 2 + 0) * 64 + l];
        short8v bl0 = W1B[(((2 * wv    ) * 4 + ks) * 2 + 1) * 64 + l];
        short8v bh1 = W1B[(((2 * wv + 1) * 4 + ks) * 2 + 0) * 64 + l];
        short8v bl1 = W1B[(((2 * wv + 1) * 4 + ks) * 2 + 1) * 64 + l];
#pragma unroll
        for (int mt = 0; mt < 4; ++mt) {
            short8v ah = *(const short8v*)&xh[mt * 16 + li][ks * 32 + g16 * 8];
            short8v al = *(const short8v*)&xl[mt * 16 + li][ks * 32 + g16 * 8];
            acc[mt][0] = MFMA16(ah, bh0, acc[mt][0]);
            acc[mt][0] = MFMA16(ah, bl0, acc[mt][0]);
            acc[mt][0] = MFMA16(al, bh0, acc[mt][0]);
            acc[mt][1] = MFMA16(ah, bh1, acc[mt][1]);
            acc[mt][1] = MFMA16(ah, bl1, acc[mt][1]);
            acc[mt][1] = MFMA16(al, bh1, acc[mt][1]);
        }
    }
    __syncthreads();   // S2: all xh/xl reads (GEMM1 + transpose) complete

    // ---- h = relu(acc + b1), re-split into xh/xl (overwrite) ----
    {
        float bv0 = b1[(2 * wv) * 16 + li];
        float bv1 = b1[(2 * wv + 1) * 16 + li];
#pragma unroll
        for (int mt = 0; mt < 4; ++mt) {
#pragma unroll
            for (int r2 = 0; r2 < 4; ++r2) {
                int row = mt * 16 + g16 * 4 + r2;
                float hv0 = fmaxf(acc[mt][0][r2] + bv0, 0.f);
                short hh0 = f2bf(hv0);
                xh[row][(2 * wv) * 16 + li] = hh0;
                xl[row][(2 * wv) * 16 + li] = f2bf(hv0 - bf2f(hh0));
                float hv1 = fmaxf(acc[mt][1][r2] + bv1, 0.f);
                short hh1 = f2bf(hv1);
                xh[row][(2 * wv + 1) * 16 + li] = hh1;
                xl[row][(2 * wv + 1) * 16 + li] = f2bf(hv1 - bf2f(hh1));
            }
        }
    }
    __syncthreads();   // S3: h complete

    // ---- GEMM2: logits = h @ W2 (wave w owns m-tile wv, both n-tiles) ----
    float4v acc2[2];
    acc2[0] = (float4v){0.f, 0.f, 0.f, 0.f};
    acc2[1] = (float4v){0.f, 0.f, 0.f, 0.f};
    const short8v* W2B = (const short8v*)wW2;
#pragma unroll
    for (int ks = 0; ks < 4; ++ks) {
        short8v ah = *(const short8v*)&xh[wv * 16 + li][ks * 32 + g16 * 8];
        short8v al = *(const short8v*)&xl[wv * 16 + li][ks * 32 + g16 * 8];
#pragma unroll
        for (int nt = 0; nt < 2; ++nt) {
            short8v bh = W2B[((nt * 4 + ks) * 2 + 0) * 64 + l];
            short8v bl = W2B[((nt * 4 + ks) * 2 + 1) * 64 + l];
            acc2[nt] = MFMA16(ah, bh, acc2[nt]);
            acc2[nt] = MFMA16(ah, bl, acc2[nt]);
            acc2[nt] = MFMA16(al, bh, acc2[nt]);
        }
    }

    // ---- softmax in registers: lane owns k={li,16+li} for rows g16*4+r2 of tile wv ----
    {
        const float scal = scaling[0];
        const float b2v0 = b2[li], b2v1 = b2[16 + li];
        const float am0 = amask[li], am1 = amask[16 + li];
        float ep_acc = 0.f;
#pragma unroll
        for (int r2 = 0; r2 < 4; ++r2) {
            int m = wv * 16 + g16 * 4 + r2;
            int gn = n0 + m;
            bool valid = gn < NN;
            float lg0 = (acc2[0][r2] + b2v0) * scal; if (am0 == 0.f) lg0 = -1e9f;
            float lg1 = (acc2[1][r2] + b2v1) * scal; if (am1 == 0.f) lg1 = -1e9f;
            float u0 = valid ? gum[(size_t)gn * KK + li] : 0.5f;
            float u1 = valid ? gum[(size_t)gn * KK + 16 + li] : 0.5f;
            float z0 = lg0 - __logf(-__logf(u0 + EPSF) + EPSF);
            float z1 = lg1 - __logf(-__logf(u1 + EPSF) + EPSF);
            float mx = fmaxf(z0, z1);
            mx = fmaxf(mx, __shfl_xor(mx, 1));
            mx = fmaxf(mx, __shfl_xor(mx, 2));
            mx = fmaxf(mx, __shfl_xor(mx, 4));
            mx = fmaxf(mx, __shfl_xor(mx, 8));
            float e0 = __expf(z0 - mx), e1 = __expf(z1 - mx);
            float sm = e0 + e1;
            sm += __shfl_xor(sm, 1);
            sm += __shfl_xor(sm, 2);
            sm += __shfl_xor(sm, 4);
            sm += __shfl_xor(sm, 8);
            float inv = 1.f / sm;
            float s0 = e0 * inv, s1 = e1 * inv;
            if (!valid) { s0 = 0.f; s1 = 0.f; }
            else {
                dout[S_OFF + (size_t)gn * KK + li] = s0;
                dout[S_OFF + (size_t)gn * KK + 16 + li] = s1;
            }
            st[li][m] = f2bf(s0);
            st[16 + li][m] = f2bf(s1);
            ep_acc += s0 * __logf(s0 + EPSF) + s1 * __logf(s1 + EPSF);
        }
        ep_acc += __shfl_xor(ep_acc, 1);
        ep_acc += __shfl_xor(ep_acc, 2);
        ep_acc += __shfl_xor(ep_acc, 4);
        ep_acc += __shfl_xor(ep_acc, 8);
        if (li == 0) atomicAdd(&s_ent, ep_acc);
    }
    __syncthreads();   // S4: st/xt/lbat ready

    // ---- stats: per-(b,k) running sums over sorted nodes ----
    {
        const int k = t & 31, ch = t >> 5;
        float rs = 0.f, rpx = 0.f, rpy = 0.f, rsq = 0.f;
        int cur_b = -1;
        for (int r = 0; r < 8; ++r) {
            int n = ch * 8 + r;
            int gn = n0 + n;
            if (gn < NN) {
                int bb = lbat[n];
                if (bb != cur_b) {
                    if (cur_b >= 0) {
                        atomicAdd(ws + WS_SB_S  + cur_b * KK + k, rs);
                        atomicAdd(ws + WS_SB_PX + cur_b * KK + k, rpx);
                        atomicAdd(ws + WS_SB_PY + cur_b * KK + k, rpy);
                        atomicAdd(ws + WS_SB_SQ + cur_b * KK + k, rsq);
                    }
                    cur_b = bb; rs = rpx = rpy = rsq = 0.f;
                }
                float sv = bf2f(st[k][n]);
                rs += sv; rpx += sv * lpx[n]; rpy += sv * lpy[n]; rsq += sv * lpsq[n];
            }
        }
        if (cur_b >= 0) {
            atomicAdd(ws + WS_SB_S  + cur_b * KK + k, rs);
            atomicAdd(ws + WS_SB_PX + cur_b * KK + k, rpx);
            atomicAdd(ws + WS_SB_PY + cur_b * KK + k, rpy);
            atomicAdd(ws + WS_SB_SQ + cur_b * KK + k, rsq);
        }
    }
    if (t == 0) atomicAdd(ws + WS_ENT, s_ent);

    // ---- pooling: out[b] += s^T x via MFMA; wave w owns c-cols [32w,32w+32), both k-tiles ----
    {
        const int b0 = lbat[0], b63 = lbat[63];
        const int ca = (2 * wv) * 16 + li;
        const int cb2 = (2 * wv + 1) * 16 + li;
        float4v p00 = (float4v){0.f, 0.f, 0.f, 0.f}, p01 = p00, p10 = p00, p11 = p00;
        if (b0 == b63) {
#pragma unroll
            for (int ksl = 0; ksl < 2; ++ksl) {
                short8v a0 = *(const short8v*)&st[li][ksl * 32 + g16 * 8];
                short8v a1 = *(const short8v*)&st[16 + li][ksl * 32 + g16 * 8];
                short8v v0 = *(const short8v*)&xt[ca][ksl * 32 + g16 * 8];
                short8v v1 = *(const short8v*)&xt[cb2][ksl * 32 + g16 * 8];
                p00 = MFMA16(a0, v0, p00);
                p01 = MFMA16(a0, v1, p01);
                p10 = MFMA16(a1, v0, p10);
                p11 = MFMA16(a1, v1, p11);
            }
            float* ob = dout + (size_t)b0 * KK * CC;
#pragma unroll
            for (int r2 = 0; r2 < 4; ++r2) {
                int k0r = g16 * 4 + r2;
                atomicAdd(ob + k0r * CC + ca, p00[r2]);
                atomicAdd(ob + k0r * CC + cb2, p01[r2]);
                atomicAdd(ob + (16 + k0r) * CC + ca, p10[r2]);
                atomicAdd(ob + (16 + k0r) * CC + cb2, p11[r2]);
            }
        } else {
            // boundary block (rare, sorted batch => 2 graphs): masked passes
            int cut = 64;
            for (int i = 1; i < 64; ++i) { if (lbat[i] != b0) { cut = i; break; } }
#pragma unroll 1
            for (int pass = 0; pass < 2; ++pass) {
                int lo = pass ? cut : 0;
                int hi = pass ? 64 : cut;
                int bb = pass ? b63 : b0;
                p00 = (float4v){0.f, 0.f, 0.f, 0.f}; p01 = p00; p10 = p00; p11 = p00;
#pragma unroll
                for (int ksl = 0; ksl < 2; ++ksl) {
                    short8v a0, a1;
#pragma unroll
                    for (int j = 0; j < 8; ++j) {
                        int i = ksl * 32 + g16 * 8 + j;
                        bool in = (i >= lo) && (i < hi);
                        a0[j] = in ? st[li][i] : (short)0;
                        a1[j] = in ? st[16 + li][i] : (short)0;
                    }
                    short8v v0 = *(const short8v*)&xt[ca][ksl * 32 + g16 * 8];
                    short8v v1 = *(const short8v*)&xt[cb2][ksl * 32 + g16 * 8];
                    p00 = MFMA16(a0, v0, p00);
                    p01 = MFMA16(a0, v1, p01);
                    p10 = MFMA16(a1, v0, p10);
                    p11 = MFMA16(a1, v1, p11);
                }
                float* ob = dout + (size_t)bb * KK * CC;
#pragma unroll
                for (int r2 = 0; r2 < 4; ++r2) {
                    int k0r = g16 * 4 + r2;
                    atomicAdd(ob + k0r * CC + ca, p00[r2]);
                    atomicAdd(ob + k0r * CC + cb2, p01[r2]);
                    atomicAdd(ob + (16 + k0r) * CC + ca, p10[r2]);
                    atomicAdd(ob + (16 + k0r) * CC + cb2, p11[r2]);
                }
            }
        }
    }
}

// ---------------- finalize losses + centroids ----------------
__global__ __launch_bounds__(256) void k_final(
    const float* __restrict__ ws, const float* __restrict__ amask,
    float* __restrict__ dout)
{
    __shared__ float avg[32], csum[32], cpx[32], cpy[32], csq[32];
    __shared__ float lmu[16][32][2];
    __shared__ float red[4];
    const int t = threadIdx.x;
    if (t < 32) {
        float a = 0.f, px = 0.f, py = 0.f, sq = 0.f;
        for (int b = 0; b < BG; ++b) {
            a  += ws[WS_SB_S  + b * KK + t];
            px += ws[WS_SB_PX + b * KK + t];
            py += ws[WS_SB_PY + b * KK + t];
            sq += ws[WS_SB_SQ + b * KK + t];
        }
        csum[t] = a; cpx[t] = px; cpy[t] = py; csq[t] = sq;
        avg[t] = a / (float)NN;
    }
    for (int idx = t; idx < BG * KK; idx += 256) {
        float den = ws[WS_SB_S + idx] + EPSF;
        float mx = ws[WS_SB_PX + idx] / den;
        float my = ws[WS_SB_PY + idx] / den;
        int b = idx >> 5, k = idx & 31;
        lmu[b][k][0] = mx; lmu[b][k][1] = my;
        dout[MU_OFF + idx * 2] = mx;
        dout[MU_OFF + idx * 2 + 1] = my;
    }
    __syncthreads();
    float sep = 0.f;
    for (int idx = t; idx < BG * KK * KK; idx += 256) {
        int b = idx >> 10, k1 = (idx >> 5) & 31, k2 = idx & 31;
        if (k1 != k2) {
            float dx = lmu[b][k1][0] - lmu[b][k2][0];
            float dy = lmu[b][k1][1] - lmu[b][k2][1];
            sep += 1.f / (dx * dx + dy * dy + 1.f);
        }
    }
    for (int off = 32; off; off >>= 1) sep += __shfl_down(sep, off);
    if ((t & 63) == 0) red[t >> 6] = sep;
    __syncthreads();
    if (t == 0) {
        float sept = red[0] + red[1] + red[2] + red[3];
        float separation = sept / ((float)(KK * (KK - 1)) + EPSF);
        float entropy = -ws[WS_ENT] / (float)NN;
        float diversity = 0.f, pruning = 0.f, msum = 0.f, entavg = 0.f, bal = 0.f, mxa = 0.f, spatial = 0.f;
        const float up = 1.f / (float)KK;
        for (int k = 0; k < KK; ++k) {
            float a = avg[k];
            diversity += up * logf(up / (a + EPSF));
            float mk = amask[k];
            pruning += fabsf(a * (1.f - mk));
            msum += mk;
            entavg -= a * logf(a + EPSF);
            bal += a * logf(a * (float)KK + EPSF);
            mxa = fmaxf(mxa, a);
            float den = csum[k] + EPSF;
            float mux = cpx[k] / den, muy = cpy[k] / den;
            spatial += csq[k] / den - (mux * mux + muy * muy);
        }
        pruning *= up;
        spatial *= up;
        const float lk = logf((float)KK);
        float collapse = ((lk - entavg) / lk + fmaxf(mxa - 2.f / (float)KK, 0.f)) * 2.0f;
        float sparsity = (msum / (float)KK) * 0.01f;
        dout[LOSS_OFF + 0] = entropy;
        dout[LOSS_OFF + 1] = diversity;
        dout[LOSS_OFF + 2] = spatial;
        dout[LOSS_OFF + 3] = pruning;
        dout[LOSS_OFF + 4] = sparsity;
        dout[LOSS_OFF + 5] = 0.f;
        dout[LOSS_OFF + 6] = collapse;
        dout[LOSS_OFF + 7] = bal;
        dout[LOSS_OFF + 8] = separation;
    }
}

extern "C" void kernel_launch(void* const* d_in, const int* in_sizes, int n_in,
                              void* d_out, int out_size, void* d_ws, size_t ws_size,
                              hipStream_t stream) {
    const float* x     = (const float*)d_in[0];
    const int*   batch = (const int*)d_in[1];
    const float* pos   = (const float*)d_in[2];
    const float* gum   = (const float*)d_in[3];
    const float* W1    = (const float*)d_in[4];
    const float* b1    = (const float*)d_in[5];
    const float* W2    = (const float*)d_in[6];
    const float* b2    = (const float*)d_in[7];
    const float* scal  = (const float*)d_in[8];
    const float* amask = (const float*)d_in[9];
    float* dout = (float*)d_out;
    float* ws   = (float*)d_ws;
    short* wW1  = (short*)((char*)d_ws + W1B_OFF_BYTES);
    short* wW2  = (short*)((char*)d_ws + W2B_OFF_BYTES);

    hipMemsetAsync(dout, 0, S_OFF * sizeof(float), stream);   // pooled-out region
    hipMemsetAsync(ws, 0, WS_TOTAL * sizeof(float), stream);  // stats accumulators

    k_prep<<<10, 256, 0, stream>>>(W1, W2, wW1, wW2);
    k_assign<<<(NN + 63) / 64, 256, 0, stream>>>(x, batch, pos, gum, b1, b2,
                                                 scal, amask, wW1, wW2, dout, ws);
    k_final<<<1, 256, 0, stream>>>(ws, amask, dout);
}

// Round 3
// 164.356 us; speedup vs baseline: 1.7071x; 1.2842x over previous
//
#include <hip/hip_runtime.h>
#include <math.h>

#define NN 100000
#define CC 128
#define KK 32
#define BG 16
#define EPSF 1e-9f

#define NTILES 1563   // ceil(NN/64)
#define NBLK 512      // 1563 = 512*3 + 27 -> blocks 0..26 get 4 tiles, rest 3

// d_out float layout: out[16][32][128] | s[100000][32] | mu[16][32][2] | losses[9]
#define S_OFF 65536
#define MU_OFF 3265536
#define LOSS_OFF 3266560

// ws float layout (stats), then W fragment buffers at byte offsets
#define WS_ENT 0
#define WS_SB_S 16
#define WS_SB_PX 528
#define WS_SB_PY 1040
#define WS_SB_SQ 1552
#define WS_TOTAL 2064

#define W1B_OFF_BYTES 16384
#define W2B_OFF_BYTES (16384 + 65536)

typedef __attribute__((ext_vector_type(8))) short short8v;
typedef __attribute__((ext_vector_type(4))) short short4v;
typedef __attribute__((ext_vector_type(4))) float float4v;

#define MFMA16(a, b, c) __builtin_amdgcn_mfma_f32_16x16x32_bf16((a), (b), (c), 0, 0, 0)

__device__ __forceinline__ short f2bf(float f) {
    unsigned u = __float_as_uint(f);
    unsigned r = (u + 0x7fffu + ((u >> 16) & 1u)) >> 16;
    return (short)r;
}
__device__ __forceinline__ float bf2f(short s) {
    return __uint_as_float(((unsigned)(unsigned short)s) << 16);
}

// ---------------- prep: split W1/W2 to bf16 hi/lo in B-fragment layout ----------------
__global__ __launch_bounds__(256) void k_prep(const float* __restrict__ W1,
                                              const float* __restrict__ W2,
                                              short* __restrict__ wW1,
                                              short* __restrict__ wW2) {
    int tid = blockIdx.x * 256 + threadIdx.x;
    if (tid < 8 * 4 * 64) {                       // W1: nt(8), ks(4), lane(64)
        int l = tid & 63, ks = (tid >> 6) & 3, nt = tid >> 8;
        int n = nt * 16 + (l & 15);
        int cb = ks * 32 + (l >> 4) * 8;
        short8v H, L;
#pragma unroll
        for (int j = 0; j < 8; ++j) {
            float v = W1[(size_t)(cb + j) * CC + n];
            short hh = f2bf(v);
            H[j] = hh;
            L[j] = f2bf(v - bf2f(hh));
        }
        ((short8v*)wW1)[((nt * 4 + ks) * 2 + 0) * 64 + l] = H;
        ((short8v*)wW1)[((nt * 4 + ks) * 2 + 1) * 64 + l] = L;
    } else if (tid < 2048 + 512) {                // W2: nt(2), ks(4), lane(64)
        int t2 = tid - 2048;
        int l = t2 & 63, ks = (t2 >> 6) & 3, nt = t2 >> 8;
        int n = nt * 16 + (l & 15);
        int cb = ks * 32 + (l >> 4) * 8;
        short8v H, L;
#pragma unroll
        for (int j = 0; j < 8; ++j) {
            float v = W2[(size_t)(cb + j) * KK + n];
            short hh = f2bf(v);
            H[j] = hh;
            L[j] = f2bf(v - bf2f(hh));
        }
        ((short8v*)wW2)[((nt * 4 + ks) * 2 + 0) * 64 + l] = H;
        ((short8v*)wW2)[((nt * 4 + ks) * 2 + 1) * 64 + l] = L;
    }
}

// ---------------- fused persistent: MLP (MFMA) + gumbel softmax + stats + pooling ----------------
__global__ __launch_bounds__(256, 2) void k_assign(
    const float* __restrict__ x, const int* __restrict__ batch,
    const float* __restrict__ pos, const float* __restrict__ gum,
    const float* __restrict__ b1, const float* __restrict__ b2,
    const float* __restrict__ scaling, const float* __restrict__ amask,
    const short* __restrict__ wW1, const short* __restrict__ wW2,
    float* __restrict__ dout, float* __restrict__ ws)
{
    __shared__ short xh[64][136];   // x hi (later h hi)
    __shared__ short xl[64][136];   // x lo (later h lo)
    __shared__ short xt[128][72];   // x^T hi (pooling B)
    __shared__ short st[32][72];    // s^T bf16 (pooling A + stats)
    __shared__ float lpx[64], lpy[64], lpsq[64];
    __shared__ int lbat[64];

    const int t = threadIdx.x;
    const int bid = blockIdx.x;
    const int t_lo = bid * 3 + (bid < 27 ? bid : 27);
    const int t_cnt = (bid < 27) ? 4 : 3;

    const int l = t & 63;
    const int wv = __builtin_amdgcn_readfirstlane(t >> 6);
    const int li = l & 15;
    const int g16 = l >> 4;
    const int cc4 = (t & 31) * 4;
    const int nb = t >> 5;
    const int ca  = (2 * wv) * 16 + li;
    const int cb2 = (2 * wv + 1) * 16 + li;
    const int sk = t & 31, sch = t >> 5;   // stats mapping

    // uniform-ish per-lane constants
    const float scal = scaling[0];
    const float b2v0 = b2[li], b2v1 = b2[16 + li];
    const float am0 = amask[li], am1 = amask[16 + li];
    const float bv0 = b1[(2 * wv) * 16 + li];
    const float bv1 = b1[(2 * wv + 1) * 16 + li];

    // prefetch registers
    float4 xv[8];
    float gu[8];
    float pxr = 0.f, pyr = 0.f;
    int bbr = BG - 1;

    // cross-tile accumulators
    float4v p00 = {0.f, 0.f, 0.f, 0.f}, p01 = p00, p10 = p00, p11 = p00;
    int p_b = -1;
    float rs = 0.f, rpx = 0.f, rpy = 0.f, rsq = 0.f;
    int cur_b = -1;
    float ep_acc = 0.f;

    auto pool_flush = [&](int bb) {
        float* ob = dout + (size_t)bb * KK * CC;
#pragma unroll
        for (int r2 = 0; r2 < 4; ++r2) {
            int k0r = g16 * 4 + r2;
            atomicAdd(ob + k0r * CC + ca, p00[r2]);
            atomicAdd(ob + k0r * CC + cb2, p01[r2]);
            atomicAdd(ob + (16 + k0r) * CC + ca, p10[r2]);
            atomicAdd(ob + (16 + k0r) * CC + cb2, p11[r2]);
        }
        p00 = (float4v){0.f, 0.f, 0.f, 0.f}; p01 = p00; p10 = p00; p11 = p00;
    };
    auto stat_flush = [&](int bb) {
        atomicAdd(ws + WS_SB_S  + bb * KK + sk, rs);
        atomicAdd(ws + WS_SB_PX + bb * KK + sk, rpx);
        atomicAdd(ws + WS_SB_PY + bb * KK + sk, rpy);
        atomicAdd(ws + WS_SB_SQ + bb * KK + sk, rsq);
        rs = rpx = rpy = rsq = 0.f;
    };

    // ---- prologue: prefetch tile t_lo ----
    {
        const int n0 = t_lo * 64;
#pragma unroll
        for (int r = 0; r < 8; ++r) {
            int gn = n0 + r * 8 + nb;
            float4 v = make_float4(0.f, 0.f, 0.f, 0.f);
            if (gn < NN) v = *(const float4*)(x + (size_t)gn * CC + cc4);
            xv[r] = v;
        }
        if (t < 64) {
            int gn = n0 + t;
            if (gn < NN) { pxr = pos[gn * 2]; pyr = pos[gn * 2 + 1]; bbr = batch[gn]; }
        }
#pragma unroll
        for (int r2 = 0; r2 < 4; ++r2) {
            int gn = n0 + wv * 16 + g16 * 4 + r2;
            bool valid = gn < NN;
            gu[r2 * 2]     = valid ? gum[(size_t)gn * KK + li]      : 0.5f;
            gu[r2 * 2 + 1] = valid ? gum[(size_t)gn * KK + 16 + li] : 0.5f;
        }
    }

#pragma unroll 1
    for (int it = 0; it < t_cnt; ++it) {
        const int tile = t_lo + it;
        const int n0 = tile * 64;

        // ---- stage prefetched x -> split bf16 LDS ----
#pragma unroll
        for (int r = 0; r < 8; ++r) {
            int n = r * 8 + nb;
            float4 v = xv[r];
            short h0 = f2bf(v.x), h1 = f2bf(v.y), h2 = f2bf(v.z), h3 = f2bf(v.w);
            short q0 = f2bf(v.x - bf2f(h0)), q1 = f2bf(v.y - bf2f(h1));
            short q2 = f2bf(v.z - bf2f(h2)), q3 = f2bf(v.w - bf2f(h3));
            *(short4v*)&xh[n][cc4] = (short4v){h0, h1, h2, h3};
            *(short4v*)&xl[n][cc4] = (short4v){q0, q1, q2, q3};
        }
        if (t < 64) {
            lpx[t] = pxr; lpy[t] = pyr; lpsq[t] = pxr * pxr + pyr * pyr; lbat[t] = bbr;
        }

        // ---- issue next tile x/pos/batch prefetch (regs consumed above) ----
        if (it + 1 < t_cnt) {
            const int n0n = n0 + 64;
#pragma unroll
            for (int r = 0; r < 8; ++r) {
                int gn = n0n + r * 8 + nb;
                float4 v = make_float4(0.f, 0.f, 0.f, 0.f);
                if (gn < NN) v = *(const float4*)(x + (size_t)gn * CC + cc4);
                xv[r] = v;
            }
            if (t < 64) {
                int gn = n0n + t;
                if (gn < NN) { pxr = pos[gn * 2]; pyr = pos[gn * 2 + 1]; bbr = batch[gn]; }
                else { pxr = 0.f; pyr = 0.f; bbr = BG - 1; }
            }
        }
        __syncthreads();   // S1: x tile + meta staged

        // ---- transpose hi(x) into xt[c][i] ----
        {
            const int c = t >> 1, hf = t & 1;
#pragma unroll
            for (int j = 0; j < 32; ++j) {
                int i = hf * 32 + j;
                xt[c][i] = xh[i][c];
            }
        }

        // ---- GEMM1: h = x @ W1, split-bf16 3-term MFMA ----
        float4v acc[4][2];
#pragma unroll
        for (int mt = 0; mt < 4; ++mt) {
            acc[mt][0] = (float4v){0.f, 0.f, 0.f, 0.f};
            acc[mt][1] = (float4v){0.f, 0.f, 0.f, 0.f};
        }
        const short8v* W1B = (const short8v*)wW1;
#pragma unroll
        for (int ks = 0; ks < 4; ++ks) {
            short8v bh0 = W1B[(((2 * wv    ) * 4 + ks) * 2 + 0) * 64 + l];
            short8v bl0 = W1B[(((2 * wv    ) * 4 + ks) * 2 + 1) * 64 + l];
            short8v bh1 = W1B[(((2 * wv + 1) * 4 + ks) * 2 + 0) * 64 + l];
            short8v bl1 = W1B[(((2 * wv + 1) * 4 + ks) * 2 + 1) * 64 + l];
#pragma unroll
            for (int mt = 0; mt < 4; ++mt) {
                short8v ah = *(const short8v*)&xh[mt * 16 + li][ks * 32 + g16 * 8];
                short8v al = *(const short8v*)&xl[mt * 16 + li][ks * 32 + g16 * 8];
                acc[mt][0] = MFMA16(ah, bh0, acc[mt][0]);
                acc[mt][0] = MFMA16(ah, bl0, acc[mt][0]);
                acc[mt][0] = MFMA16(al, bh0, acc[mt][0]);
                acc[mt][1] = MFMA16(ah, bh1, acc[mt][1]);
                acc[mt][1] = MFMA16(ah, bl1, acc[mt][1]);
                acc[mt][1] = MFMA16(al, bh1, acc[mt][1]);
            }
        }
        __syncthreads();   // S2: xh/xl reads (GEMM1 + transpose) done

        // ---- h = relu(acc + b1), re-split into xh/xl ----
#pragma unroll
        for (int mt = 0; mt < 4; ++mt) {
#pragma unroll
            for (int r2 = 0; r2 < 4; ++r2) {
                int row = mt * 16 + g16 * 4 + r2;
                float hv0 = fmaxf(acc[mt][0][r2] + bv0, 0.f);
                short hh0 = f2bf(hv0);
                xh[row][(2 * wv) * 16 + li] = hh0;
                xl[row][(2 * wv) * 16 + li] = f2bf(hv0 - bf2f(hh0));
                float hv1 = fmaxf(acc[mt][1][r2] + bv1, 0.f);
                short hh1 = f2bf(hv1);
                xh[row][(2 * wv + 1) * 16 + li] = hh1;
                xl[row][(2 * wv + 1) * 16 + li] = f2bf(hv1 - bf2f(hh1));
            }
        }
        __syncthreads();   // S3: h complete

        // ---- GEMM2: logits = h @ W2 ----
        float4v acc2[2];
        acc2[0] = (float4v){0.f, 0.f, 0.f, 0.f};
        acc2[1] = (float4v){0.f, 0.f, 0.f, 0.f};
        const short8v* W2B = (const short8v*)wW2;
#pragma unroll
        for (int ks = 0; ks < 4; ++ks) {
            short8v ah = *(const short8v*)&xh[wv * 16 + li][ks * 32 + g16 * 8];
            short8v al = *(const short8v*)&xl[wv * 16 + li][ks * 32 + g16 * 8];
#pragma unroll
            for (int nt = 0; nt < 2; ++nt) {
                short8v bh = W2B[((nt * 4 + ks) * 2 + 0) * 64 + l];
                short8v bl = W2B[((nt * 4 + ks) * 2 + 1) * 64 + l];
                acc2[nt] = MFMA16(ah, bh, acc2[nt]);
                acc2[nt] = MFMA16(ah, bl, acc2[nt]);
                acc2[nt] = MFMA16(al, bh, acc2[nt]);
            }
        }

        // ---- softmax in registers ----
#pragma unroll
        for (int r2 = 0; r2 < 4; ++r2) {
            int m = wv * 16 + g16 * 4 + r2;
            int gn = n0 + m;
            bool valid = gn < NN;
            float lg0 = (acc2[0][r2] + b2v0) * scal; if (am0 == 0.f) lg0 = -1e9f;
            float lg1 = (acc2[1][r2] + b2v1) * scal; if (am1 == 0.f) lg1 = -1e9f;
            float z0 = lg0 - __logf(-__logf(gu[r2 * 2] + EPSF) + EPSF);
            float z1 = lg1 - __logf(-__logf(gu[r2 * 2 + 1] + EPSF) + EPSF);
            float mx = fmaxf(z0, z1);
            mx = fmaxf(mx, __shfl_xor(mx, 1));
            mx = fmaxf(mx, __shfl_xor(mx, 2));
            mx = fmaxf(mx, __shfl_xor(mx, 4));
            mx = fmaxf(mx, __shfl_xor(mx, 8));
            float e0 = __expf(z0 - mx), e1 = __expf(z1 - mx);
            float sm = e0 + e1;
            sm += __shfl_xor(sm, 1);
            sm += __shfl_xor(sm, 2);
            sm += __shfl_xor(sm, 4);
            sm += __shfl_xor(sm, 8);
            float inv = 1.f / sm;
            float s0 = e0 * inv, s1 = e1 * inv;
            if (!valid) { s0 = 0.f; s1 = 0.f; }
            else {
                dout[S_OFF + (size_t)gn * KK + li] = s0;
                dout[S_OFF + (size_t)gn * KK + 16 + li] = s1;
            }
            st[li][m] = f2bf(s0);
            st[16 + li][m] = f2bf(s1);
            ep_acc += s0 * __logf(s0 + EPSF) + s1 * __logf(s1 + EPSF);
        }

        // ---- issue next tile gumbel prefetch (gu consumed above) ----
        if (it + 1 < t_cnt) {
            const int n0n = n0 + 64;
#pragma unroll
            for (int r2 = 0; r2 < 4; ++r2) {
                int gn = n0n + wv * 16 + g16 * 4 + r2;
                bool valid = gn < NN;
                gu[r2 * 2]     = valid ? gum[(size_t)gn * KK + li]      : 0.5f;
                gu[r2 * 2 + 1] = valid ? gum[(size_t)gn * KK + 16 + li] : 0.5f;
            }
        }
        __syncthreads();   // S4: st ready

        // ---- stats: per-(b,k) running sums, cross-tile carry ----
        for (int r = 0; r < 8; ++r) {
            int n = sch * 8 + r;
            int gn = n0 + n;
            if (gn < NN) {
                int bb = lbat[n];
                if (bb != cur_b) {
                    if (cur_b >= 0) stat_flush(cur_b);
                    cur_b = bb;
                }
                float sv = bf2f(st[sk][n]);
                rs += sv; rpx += sv * lpx[n]; rpy += sv * lpy[n]; rsq += sv * lpsq[n];
            }
        }

        // ---- pooling: accumulate s^T x into regs, flush per graph segment ----
        {
            const int b0 = lbat[0], b63 = lbat[63];
            if (p_b >= 0 && p_b != b0) pool_flush(p_b);
            if (b0 == b63) {
#pragma unroll
                for (int ksl = 0; ksl < 2; ++ksl) {
                    short8v a0 = *(const short8v*)&st[li][ksl * 32 + g16 * 8];
                    short8v a1 = *(const short8v*)&st[16 + li][ksl * 32 + g16 * 8];
                    short8v v0 = *(const short8v*)&xt[ca][ksl * 32 + g16 * 8];
                    short8v v1 = *(const short8v*)&xt[cb2][ksl * 32 + g16 * 8];
                    p00 = MFMA16(a0, v0, p00);
                    p01 = MFMA16(a0, v1, p01);
                    p10 = MFMA16(a1, v0, p10);
                    p11 = MFMA16(a1, v1, p11);
                }
                p_b = b0;
            } else {
                int cut = 64;
                for (int i = 1; i < 64; ++i) { if (lbat[i] != b0) { cut = i; break; } }
#pragma unroll 1
                for (int pass = 0; pass < 2; ++pass) {
                    int lo = pass ? cut : 0;
                    int hi = pass ? 64 : cut;
#pragma unroll
                    for (int ksl = 0; ksl < 2; ++ksl) {
                        short8v a0, a1;
#pragma unroll
                        for (int j = 0; j < 8; ++j) {
                            int i = ksl * 32 + g16 * 8 + j;
                            bool in = (i >= lo) && (i < hi);
                            a0[j] = in ? st[li][i] : (short)0;
                            a1[j] = in ? st[16 + li][i] : (short)0;
                        }
                        short8v v0 = *(const short8v*)&xt[ca][ksl * 32 + g16 * 8];
                        short8v v1 = *(const short8v*)&xt[cb2][ksl * 32 + g16 * 8];
                        p00 = MFMA16(a0, v0, p00);
                        p01 = MFMA16(a0, v1, p01);
                        p10 = MFMA16(a1, v0, p10);
                        p11 = MFMA16(a1, v1, p11);
                    }
                    if (pass == 0) pool_flush(b0);
                }
                p_b = b63;
            }
        }
        __syncthreads();   // S5: LDS consumers done before next stage
    }

    // ---- epilogue: final flushes + entropy reduction ----
    if (p_b >= 0) pool_flush(p_b);
    if (cur_b >= 0) stat_flush(cur_b);
    ep_acc += __shfl_xor(ep_acc, 1);
    ep_acc += __shfl_xor(ep_acc, 2);
    ep_acc += __shfl_xor(ep_acc, 4);
    ep_acc += __shfl_xor(ep_acc, 8);
    ep_acc += __shfl_xor(ep_acc, 16);
    ep_acc += __shfl_xor(ep_acc, 32);
    if (l == 0) atomicAdd(ws + WS_ENT, ep_acc);
}

// ---------------- finalize losses + centroids ----------------
__global__ __launch_bounds__(256) void k_final(
    const float* __restrict__ ws, const float* __restrict__ amask,
    float* __restrict__ dout)
{
    __shared__ float avg[32], csum[32], cpx[32], cpy[32], csq[32];
    __shared__ float lmu[16][32][2];
    __shared__ float red[4];
    const int t = threadIdx.x;
    if (t < 32) {
        float a = 0.f, px = 0.f, py = 0.f, sq = 0.f;
        for (int b = 0; b < BG; ++b) {
            a  += ws[WS_SB_S  + b * KK + t];
            px += ws[WS_SB_PX + b * KK + t];
            py += ws[WS_SB_PY + b * KK + t];
            sq += ws[WS_SB_SQ + b * KK + t];
        }
        csum[t] = a; cpx[t] = px; cpy[t] = py; csq[t] = sq;
        avg[t] = a / (float)NN;
    }
    for (int idx = t; idx < BG * KK; idx += 256) {
        float den = ws[WS_SB_S + idx] + EPSF;
        float mx = ws[WS_SB_PX + idx] / den;
        float my = ws[WS_SB_PY + idx] / den;
        int b = idx >> 5, k = idx & 31;
        lmu[b][k][0] = mx; lmu[b][k][1] = my;
        dout[MU_OFF + idx * 2] = mx;
        dout[MU_OFF + idx * 2 + 1] = my;
    }
    __syncthreads();
    float sep = 0.f;
    for (int idx = t; idx < BG * KK * KK; idx += 256) {
        int b = idx >> 10, k1 = (idx >> 5) & 31, k2 = idx & 31;
        if (k1 != k2) {
            float dx = lmu[b][k1][0] - lmu[b][k2][0];
            float dy = lmu[b][k1][1] - lmu[b][k2][1];
            sep += 1.f / (dx * dx + dy * dy + 1.f);
        }
    }
    for (int off = 32; off; off >>= 1) sep += __shfl_down(sep, off);
    if ((t & 63) == 0) red[t >> 6] = sep;
    __syncthreads();
    if (t == 0) {
        float sept = red[0] + red[1] + red[2] + red[3];
        float separation = sept / ((float)(KK * (KK - 1)) + EPSF);
        float entropy = -ws[WS_ENT] / (float)NN;
        float diversity = 0.f, pruning = 0.f, msum = 0.f, entavg = 0.f, bal = 0.f, mxa = 0.f, spatial = 0.f;
        const float up = 1.f / (float)KK;
        for (int k = 0; k < KK; ++k) {
            float a = avg[k];
            diversity += up * logf(up / (a + EPSF));
            float mk = amask[k];
            pruning += fabsf(a * (1.f - mk));
            msum += mk;
            entavg -= a * logf(a + EPSF);
            bal += a * logf(a * (float)KK + EPSF);
            mxa = fmaxf(mxa, a);
            float den = csum[k] + EPSF;
            float mux = cpx[k] / den, muy = cpy[k] / den;
            spatial += csq[k] / den - (mux * mux + muy * muy);
        }
        pruning *= up;
        spatial *= up;
        const float lk = logf((float)KK);
        float collapse = ((lk - entavg) / lk + fmaxf(mxa - 2.f / (float)KK, 0.f)) * 2.0f;
        float sparsity = (msum / (float)KK) * 0.01f;
        dout[LOSS_OFF + 0] = entropy;
        dout[LOSS_OFF + 1] = diversity;
        dout[LOSS_OFF + 2] = spatial;
        dout[LOSS_OFF + 3] = pruning;
        dout[LOSS_OFF + 4] = sparsity;
        dout[LOSS_OFF + 5] = 0.f;
        dout[LOSS_OFF + 6] = collapse;
        dout[LOSS_OFF + 7] = bal;
        dout[LOSS_OFF + 8] = separation;
    }
}

extern "C" void kernel_launch(void* const* d_in, const int* in_sizes, int n_in,
                              void* d_out, int out_size, void* d_ws, size_t ws_size,
                              hipStream_t stream) {
    const float* x     = (const float*)d_in[0];
    const int*   batch = (const int*)d_in[1];
    const float* pos   = (const float*)d_in[2];
    const float* gum   = (const float*)d_in[3];
    const float* W1    = (const float*)d_in[4];
    const float* b1    = (const float*)d_in[5];
    const float* W2    = (const float*)d_in[6];
    const float* b2    = (const float*)d_in[7];
    const float* scal  = (const float*)d_in[8];
    const float* amask = (const float*)d_in[9];
    float* dout = (float*)d_out;
    float* ws   = (float*)d_ws;
    short* wW1  = (short*)((char*)d_ws + W1B_OFF_BYTES);
    short* wW2  = (short*)((char*)d_ws + W2B_OFF_BYTES);

    hipMemsetAsync(dout, 0, S_OFF * sizeof(float), stream);   // pooled-out region
    hipMemsetAsync(ws, 0, WS_TOTAL * sizeof(float), stream);  // stats accumulators

    k_prep<<<10, 256, 0, stream>>>(W1, W2, wW1, wW2);
    k_assign<<<NBLK, 256, 0, stream>>>(x, batch, pos, gum, b1, b2,
                                       scal, amask, wW1, wW2, dout, ws);
    k_final<<<1, 256, 0, stream>>>(ws, amask, dout);
}

// Round 6
// 163.750 us; speedup vs baseline: 1.7134x; 1.0037x over previous
//
#include <hip/hip_runtime.h>
#include <math.h>

#define NN 100000
#define CC 128
#define KK 32
#define BG 16
#define EPSF 1e-9f

#define NTILES 1563   // ceil(NN/64)
#define NBLK 768      // 1563 = 27*3 + 741*2

// d_out float layout: out[16][32][128] | s[100000][32] | mu[16][32][2] | losses[9]
#define S_OFF 65536
#define MU_OFF 3265536
#define LOSS_OFF 3266560

// ws float layout (stats), then W fragment buffers at byte offsets
#define WS_ENT 0
#define WS_SB_S 16
#define WS_SB_PX 528
#define WS_SB_PY 1040
#define WS_SB_SQ 1552
#define WS_TOTAL 2064

#define W1B_OFF_BYTES 16384
#define W2B_OFF_BYTES (16384 + 32768)

typedef __attribute__((ext_vector_type(8))) _Float16 half8;
typedef __attribute__((ext_vector_type(4))) _Float16 half4v;
typedef __attribute__((ext_vector_type(4))) float float4v;

#define MFMAH(a, b, c) __builtin_amdgcn_mfma_f32_16x16x32_f16((a), (b), (c), 0, 0, 0)

// ---------------- prep: W1/W2 -> fp16 B-fragment layout ----------------
// B-frag for mfma_16x16x32: lane l holds B[k'][n], k' = ks*32 + (l>>4)*8 + j, n = nt*16 + (l&15)
__global__ __launch_bounds__(256) void k_prep(const float* __restrict__ W1,
                                              const float* __restrict__ W2,
                                              _Float16* __restrict__ wW1,
                                              _Float16* __restrict__ wW2) {
    int tid = blockIdx.x * 256 + threadIdx.x;
    if (tid < 8 * 4 * 64) {                       // W1: nt(8), ks(4), lane(64)
        int l = tid & 63, ks = (tid >> 6) & 3, nt = tid >> 8;
        int n = nt * 16 + (l & 15);
        int cb = ks * 32 + (l >> 4) * 8;
        half8 H;
#pragma unroll
        for (int j = 0; j < 8; ++j) H[j] = (_Float16)W1[(size_t)(cb + j) * CC + n];
        ((half8*)wW1)[(nt * 4 + ks) * 64 + l] = H;
    } else if (tid < 2048 + 512) {                // W2: nt(2), ks(4), lane(64)
        int t2 = tid - 2048;
        int l = t2 & 63, ks = (t2 >> 6) & 3, nt = t2 >> 8;
        int n = nt * 16 + (l & 15);
        int cb = ks * 32 + (l >> 4) * 8;
        half8 H;
#pragma unroll
        for (int j = 0; j < 8; ++j) H[j] = (_Float16)W2[(size_t)(cb + j) * KK + n];
        ((half8*)wW2)[(nt * 4 + ks) * 64 + l] = H;
    }
}

// ---------------- fused persistent: MLP (fp16 MFMA) + gumbel softmax + stats + pooling ----------------
__global__ __launch_bounds__(256, 3) void k_assign(
    const float* __restrict__ x, const int* __restrict__ batch,
    const float* __restrict__ pos, const float* __restrict__ gum,
    const float* __restrict__ b1, const float* __restrict__ b2,
    const float* __restrict__ scaling, const float* __restrict__ amask,
    const _Float16* __restrict__ wW1, const _Float16* __restrict__ wW2,
    float* __restrict__ dout, float* __restrict__ ws)
{
    __shared__ _Float16 xh[64][136];   // x fp16, overwritten by h after S2
    __shared__ _Float16 st[32][72];    // s^T fp16 (pooling A + stats)
    __shared__ float lpx[64], lpy[64], lpsq[64];
    __shared__ int lbat[64];

    const int t = threadIdx.x;
    const int bid = blockIdx.x;
    const int t_lo = bid * 2 + (bid < 27 ? bid : 27);
    const int t_cnt = (bid < 27) ? 3 : 2;

    const int l = t & 63;
    const int wv = __builtin_amdgcn_readfirstlane(t >> 6);
    const int li = l & 15;
    const int g16 = l >> 4;
    const int cc4 = (t & 31) * 4;
    const int nb = t >> 5;
    const int ca  = (2 * wv) * 16 + li;     // pooling c-col 0
    const int cb2 = (2 * wv + 1) * 16 + li; // pooling c-col 1
    const int sk = t & 31, sch = t >> 5;    // stats mapping

    const float scal = scaling[0];
    const float b2v0 = b2[li], b2v1 = b2[16 + li];
    const float am0 = amask[li], am1 = amask[16 + li];
    const float bv0 = b1[(2 * wv) * 16 + li];
    const float bv1 = b1[(2 * wv + 1) * 16 + li];

    // prefetch registers
    float4 xv[8];
    float gu[8];
    float pxr = 0.f, pyr = 0.f;
    int bbr = BG - 1;

    // cross-tile accumulators
    float4v p00 = {0.f, 0.f, 0.f, 0.f}, p01 = p00, p10 = p00, p11 = p00;
    int p_b = -1;
    float rs = 0.f, rpx = 0.f, rpy = 0.f, rsq = 0.f;
    int cur_b = -1;
    float ep_acc = 0.f;

    auto pool_flush = [&](int bb) {
        float* ob = dout + (size_t)bb * KK * CC;
#pragma unroll
        for (int r2 = 0; r2 < 4; ++r2) {
            int k0r = g16 * 4 + r2;
            atomicAdd(ob + k0r * CC + ca, p00[r2]);
            atomicAdd(ob + k0r * CC + cb2, p01[r2]);
            atomicAdd(ob + (16 + k0r) * CC + ca, p10[r2]);
            atomicAdd(ob + (16 + k0r) * CC + cb2, p11[r2]);
        }
        p00 = (float4v){0.f, 0.f, 0.f, 0.f}; p01 = p00; p10 = p00; p11 = p00;
    };
    auto stat_flush = [&](int bb) {
        atomicAdd(ws + WS_SB_S  + bb * KK + sk, rs);
        atomicAdd(ws + WS_SB_PX + bb * KK + sk, rpx);
        atomicAdd(ws + WS_SB_PY + bb * KK + sk, rpy);
        atomicAdd(ws + WS_SB_SQ + bb * KK + sk, rsq);
        rs = rpx = rpy = rsq = 0.f;
    };

    // ---- prologue: prefetch tile t_lo ----
    {
        const int n0 = t_lo * 64;
#pragma unroll
        for (int r = 0; r < 8; ++r) {
            int gn = n0 + r * 8 + nb;
            float4 v = make_float4(0.f, 0.f, 0.f, 0.f);
            if (gn < NN) v = *(const float4*)(x + (size_t)gn * CC + cc4);
            xv[r] = v;
        }
        if (t < 64) {
            int gn = n0 + t;
            if (gn < NN) { pxr = pos[gn * 2]; pyr = pos[gn * 2 + 1]; bbr = batch[gn]; }
        }
#pragma unroll
        for (int r2 = 0; r2 < 4; ++r2) {
            int gn = n0 + wv * 16 + g16 * 4 + r2;
            bool valid = gn < NN;
            gu[r2 * 2]     = valid ? gum[(size_t)gn * KK + li]      : 0.5f;
            gu[r2 * 2 + 1] = valid ? gum[(size_t)gn * KK + 16 + li] : 0.5f;
        }
    }

#pragma unroll 1
    for (int it = 0; it < t_cnt; ++it) {
        const int n0 = (t_lo + it) * 64;

        // ---- stage prefetched x -> fp16 LDS ----
#pragma unroll
        for (int r = 0; r < 8; ++r) {
            int n = r * 8 + nb;
            float4 v = xv[r];
            *(half4v*)&xh[n][cc4] =
                (half4v){(_Float16)v.x, (_Float16)v.y, (_Float16)v.z, (_Float16)v.w};
        }
        if (t < 64) {
            lpx[t] = pxr; lpy[t] = pyr; lpsq[t] = pxr * pxr + pyr * pyr; lbat[t] = bbr;
        }

        // ---- issue next tile x/pos/batch prefetch ----
        if (it + 1 < t_cnt) {
            const int n0n = n0 + 64;
#pragma unroll
            for (int r = 0; r < 8; ++r) {
                int gn = n0n + r * 8 + nb;
                float4 v = make_float4(0.f, 0.f, 0.f, 0.f);
                if (gn < NN) v = *(const float4*)(x + (size_t)gn * CC + cc4);
                xv[r] = v;
            }
            if (t < 64) {
                int gn = n0n + t;
                if (gn < NN) { pxr = pos[gn * 2]; pyr = pos[gn * 2 + 1]; bbr = batch[gn]; }
                else { pxr = 0.f; pyr = 0.f; bbr = BG - 1; }
            }
        }
        __syncthreads();   // S1: x tile + meta staged

        // ---- pooling B-frags: read x column-slices from xh into regs (before h overwrite)
        // frag elem j = x[i][c], i = ksl*32 + g16*8 + j
        half8 vx00, vx01, vx10, vx11;   // [ksl][col]
#pragma unroll
        for (int j = 0; j < 8; ++j) {
            vx00[j] = xh[     g16 * 8 + j][ca];
            vx01[j] = xh[     g16 * 8 + j][cb2];
            vx10[j] = xh[32 + g16 * 8 + j][ca];
            vx11[j] = xh[32 + g16 * 8 + j][cb2];
        }

        // ---- GEMM1: h = x @ W1 (fp16) ----
        float4v acc[4][2];
#pragma unroll
        for (int mt = 0; mt < 4; ++mt) {
            acc[mt][0] = (float4v){0.f, 0.f, 0.f, 0.f};
            acc[mt][1] = (float4v){0.f, 0.f, 0.f, 0.f};
        }
        const half8* W1B = (const half8*)wW1;
#pragma unroll
        for (int ks = 0; ks < 4; ++ks) {
            half8 bh0 = W1B[((2 * wv    ) * 4 + ks) * 64 + l];
            half8 bh1 = W1B[((2 * wv + 1) * 4 + ks) * 64 + l];
#pragma unroll
            for (int mt = 0; mt < 4; ++mt) {
                half8 ah = *(const half8*)&xh[mt * 16 + li][ks * 32 + g16 * 8];
                acc[mt][0] = MFMAH(ah, bh0, acc[mt][0]);
                acc[mt][1] = MFMAH(ah, bh1, acc[mt][1]);
            }
        }
        __syncthreads();   // S2: all x reads done

        // ---- h = relu(acc + b1) -> xh (fp16) ----
#pragma unroll
        for (int mt = 0; mt < 4; ++mt) {
#pragma unroll
            for (int r2 = 0; r2 < 4; ++r2) {
                int row = mt * 16 + g16 * 4 + r2;
                xh[row][(2 * wv) * 16 + li]     = (_Float16)fmaxf(acc[mt][0][r2] + bv0, 0.f);
                xh[row][(2 * wv + 1) * 16 + li] = (_Float16)fmaxf(acc[mt][1][r2] + bv1, 0.f);
            }
        }
        __syncthreads();   // S3: h ready

        // ---- GEMM2: logits = h @ W2 ----
        float4v acc2[2];
        acc2[0] = (float4v){0.f, 0.f, 0.f, 0.f};
        acc2[1] = (float4v){0.f, 0.f, 0.f, 0.f};
        const half8* W2B = (const half8*)wW2;
#pragma unroll
        for (int ks = 0; ks < 4; ++ks) {
            half8 ah = *(const half8*)&xh[wv * 16 + li][ks * 32 + g16 * 8];
            acc2[0] = MFMAH(ah, W2B[(0 * 4 + ks) * 64 + l], acc2[0]);
            acc2[1] = MFMAH(ah, W2B[(1 * 4 + ks) * 64 + l], acc2[1]);
        }

        // ---- softmax in registers; lane owns k={li,16+li} of rows g16*4+r2, m-tile wv ----
#pragma unroll
        for (int r2 = 0; r2 < 4; ++r2) {
            int m = wv * 16 + g16 * 4 + r2;
            int gn = n0 + m;
            bool valid = gn < NN;
            float lg0 = (acc2[0][r2] + b2v0) * scal; if (am0 == 0.f) lg0 = -1e9f;
            float lg1 = (acc2[1][r2] + b2v1) * scal; if (am1 == 0.f) lg1 = -1e9f;
            float z0 = lg0 - __logf(-__logf(gu[r2 * 2] + EPSF) + EPSF);
            float z1 = lg1 - __logf(-__logf(gu[r2 * 2 + 1] + EPSF) + EPSF);
            float mx = fmaxf(z0, z1);
            mx = fmaxf(mx, __shfl_xor(mx, 1));
            mx = fmaxf(mx, __shfl_xor(mx, 2));
            mx = fmaxf(mx, __shfl_xor(mx, 4));
            mx = fmaxf(mx, __shfl_xor(mx, 8));
            float e0 = __expf(z0 - mx), e1 = __expf(z1 - mx);
            float sm = e0 + e1;
            sm += __shfl_xor(sm, 1);
            sm += __shfl_xor(sm, 2);
            sm += __shfl_xor(sm, 4);
            sm += __shfl_xor(sm, 8);
            float inv = 1.f / sm;
            float s0 = e0 * inv, s1 = e1 * inv;
            if (!valid) { s0 = 0.f; s1 = 0.f; }
            else {
                dout[S_OFF + (size_t)gn * KK + li] = s0;
                dout[S_OFF + (size_t)gn * KK + 16 + li] = s1;
            }
            st[li][m] = (_Float16)s0;
            st[16 + li][m] = (_Float16)s1;
            ep_acc += s0 * __logf(s0 + EPSF) + s1 * __logf(s1 + EPSF);
        }

        // ---- next tile gumbel prefetch ----
        if (it + 1 < t_cnt) {
            const int n0n = n0 + 64;
#pragma unroll
            for (int r2 = 0; r2 < 4; ++r2) {
                int gn = n0n + wv * 16 + g16 * 4 + r2;
                bool valid = gn < NN;
                gu[r2 * 2]     = valid ? gum[(size_t)gn * KK + li]      : 0.5f;
                gu[r2 * 2 + 1] = valid ? gum[(size_t)gn * KK + 16 + li] : 0.5f;
            }
        }
        __syncthreads();   // S4: st ready

        // ---- stats: per-(b,k) running sums ----
        for (int r = 0; r < 8; ++r) {
            int n = sch * 8 + r;
            int gn = n0 + n;
            if (gn < NN) {
                int bb = lbat[n];
                if (bb != cur_b) {
                    if (cur_b >= 0) stat_flush(cur_b);
                    cur_b = bb;
                }
                float sv = (float)st[sk][n];
                rs += sv; rpx += sv * lpx[n]; rpy += sv * lpy[n]; rsq += sv * lpsq[n];
            }
        }

        // ---- pooling: accumulate s^T x, flush per graph segment ----
        {
            const int b0 = lbat[0], b63 = lbat[63];
            if (p_b >= 0 && p_b != b0) pool_flush(p_b);
            if (b0 == b63) {
#pragma unroll
                for (int ksl = 0; ksl < 2; ++ksl) {
                    half8 a0 = *(const half8*)&st[li][ksl * 32 + g16 * 8];
                    half8 a1 = *(const half8*)&st[16 + li][ksl * 32 + g16 * 8];
                    half8 v0 = ksl ? vx10 : vx00;
                    half8 v1 = ksl ? vx11 : vx01;
                    p00 = MFMAH(a0, v0, p00);
                    p01 = MFMAH(a0, v1, p01);
                    p10 = MFMAH(a1, v0, p10);
                    p11 = MFMAH(a1, v1, p11);
                }
                p_b = b0;
            } else {
                int cut = 64;
                for (int i = 1; i < 64; ++i) { if (lbat[i] != b0) { cut = i; break; } }
#pragma unroll 1
                for (int pass = 0; pass < 2; ++pass) {
                    int lo = pass ? cut : 0;
                    int hi = pass ? 64 : cut;
#pragma unroll
                    for (int ksl = 0; ksl < 2; ++ksl) {
                        half8 a0, a1;
#pragma unroll
                        for (int j = 0; j < 8; ++j) {
                            int i = ksl * 32 + g16 * 8 + j;
                            bool in = (i >= lo) && (i < hi);
                            a0[j] = in ? st[li][i] : (_Float16)0.f;
                            a1[j] = in ? st[16 + li][i] : (_Float16)0.f;
                        }
                        half8 v0 = ksl ? vx10 : vx00;
                        half8 v1 = ksl ? vx11 : vx01;
                        p00 = MFMAH(a0, v0, p00);
                        p01 = MFMAH(a0, v1, p01);
                        p10 = MFMAH(a1, v0, p10);
                        p11 = MFMAH(a1, v1, p11);
                    }
                    if (pass == 0) pool_flush(b0);
                }
                p_b = b63;
            }
        }
        __syncthreads();   // S5: st/meta reads done before next staging
    }

    // ---- epilogue ----
    if (p_b >= 0) pool_flush(p_b);
    if (cur_b >= 0) stat_flush(cur_b);
    ep_acc += __shfl_xor(ep_acc, 1);
    ep_acc += __shfl_xor(ep_acc, 2);
    ep_acc += __shfl_xor(ep_acc, 4);
    ep_acc += __shfl_xor(ep_acc, 8);
    ep_acc += __shfl_xor(ep_acc, 16);
    ep_acc += __shfl_xor(ep_acc, 32);
    if (l == 0) atomicAdd(ws + WS_ENT, ep_acc);
}

// ---------------- finalize losses + centroids ----------------
__global__ __launch_bounds__(256) void k_final(
    const float* __restrict__ ws, const float* __restrict__ amask,
    float* __restrict__ dout)
{
    __shared__ float avg[32], csum[32], cpx[32], cpy[32], csq[32];
    __shared__ float lmu[16][32][2];
    __shared__ float red[4];
    const int t = threadIdx.x;
    if (t < 32) {
        float a = 0.f, px = 0.f, py = 0.f, sq = 0.f;
        for (int b = 0; b < BG; ++b) {
            a  += ws[WS_SB_S  + b * KK + t];
            px += ws[WS_SB_PX + b * KK + t];
            py += ws[WS_SB_PY + b * KK + t];
            sq += ws[WS_SB_SQ + b * KK + t];
        }
        csum[t] = a; cpx[t] = px; cpy[t] = py; csq[t] = sq;
        avg[t] = a / (float)NN;
    }
    for (int idx = t; idx < BG * KK; idx += 256) {
        float den = ws[WS_SB_S + idx] + EPSF;
        float mx = ws[WS_SB_PX + idx] / den;
        float my = ws[WS_SB_PY + idx] / den;
        int b = idx >> 5, k = idx & 31;
        lmu[b][k][0] = mx; lmu[b][k][1] = my;
        dout[MU_OFF + idx * 2] = mx;
        dout[MU_OFF + idx * 2 + 1] = my;
    }
    __syncthreads();
    float sep = 0.f;
    for (int idx = t; idx < BG * KK * KK; idx += 256) {
        int b = idx >> 10, k1 = (idx >> 5) & 31, k2 = idx & 31;
        if (k1 != k2) {
            float dx = lmu[b][k1][0] - lmu[b][k2][0];
            float dy = lmu[b][k1][1] - lmu[b][k2][1];
            sep += 1.f / (dx * dx + dy * dy + 1.f);
        }
    }
    for (int off = 32; off; off >>= 1) sep += __shfl_down(sep, off);
    if ((t & 63) == 0) red[t >> 6] = sep;
    __syncthreads();
    if (t == 0) {
        float sept = red[0] + red[1] + red[2] + red[3];
        float separation = sept / ((float)(KK * (KK - 1)) + EPSF);
        float entropy = -ws[WS_ENT] / (float)NN;
        float diversity = 0.f, pruning = 0.f, msum = 0.f, entavg = 0.f, bal = 0.f, mxa = 0.f, spatial = 0.f;
        const float up = 1.f / (float)KK;
        for (int k = 0; k < KK; ++k) {
            float a = avg[k];
            diversity += up * logf(up / (a + EPSF));
            float mk = amask[k];
            pruning += fabsf(a * (1.f - mk));
            msum += mk;
            entavg -= a * logf(a + EPSF);
            bal += a * logf(a * (float)KK + EPSF);
            mxa = fmaxf(mxa, a);
            float den = csum[k] + EPSF;
            float mux = cpx[k] / den, muy = cpy[k] / den;
            spatial += csq[k] / den - (mux * mux + muy * muy);
        }
        pruning *= up;
        spatial *= up;
        const float lk = logf((float)KK);
        float collapse = ((lk - entavg) / lk + fmaxf(mxa - 2.f / (float)KK, 0.f)) * 2.0f;
        float sparsity = (msum / (float)KK) * 0.01f;
        dout[LOSS_OFF + 0] = entropy;
        dout[LOSS_OFF + 1] = diversity;
        dout[LOSS_OFF + 2] = spatial;
        dout[LOSS_OFF + 3] = pruning;
        dout[LOSS_OFF + 4] = sparsity;
        dout[LOSS_OFF + 5] = 0.f;
        dout[LOSS_OFF + 6] = collapse;
        dout[LOSS_OFF + 7] = bal;
        dout[LOSS_OFF + 8] = separation;
    }
}

extern "C" void kernel_launch(void* const* d_in, const int* in_sizes, int n_in,
                              void* d_out, int out_size, void* d_ws, size_t ws_size,
                              hipStream_t stream) {
    const float* x     = (const float*)d_in[0];
    const int*   batch = (const int*)d_in[1];
    const float* pos   = (const float*)d_in[2];
    const float* gum   = (const float*)d_in[3];
    const float* W1    = (const float*)d_in[4];
    const float* b1    = (const float*)d_in[5];
    const float* W2    = (const float*)d_in[6];
    const float* b2    = (const float*)d_in[7];
    const float* scal  = (const float*)d_in[8];
    const float* amask = (const float*)d_in[9];
    float* dout = (float*)d_out;
    float* ws   = (float*)d_ws;
    _Float16* wW1 = (_Float16*)((char*)d_ws + W1B_OFF_BYTES);
    _Float16* wW2 = (_Float16*)((char*)d_ws + W2B_OFF_BYTES);

    hipMemsetAsync(dout, 0, S_OFF * sizeof(float), stream);   // pooled-out region
    hipMemsetAsync(ws, 0, WS_TOTAL * sizeof(float), stream);  // stats accumulators

    k_prep<<<10, 256, 0, stream>>>(W1, W2, wW1, wW2);
    k_assign<<<NBLK, 256, 0, stream>>>(x, batch, pos, gum, b1, b2,
                                       scal, amask, wW1, wW2, dout, ws);
    k_final<<<1, 256, 0, stream>>>(ws, amask, dout);
}

// Round 7
// 139.432 us; speedup vs baseline: 2.0122x; 1.1744x over previous
//
#include <hip/hip_runtime.h>
#include <math.h>

#define NN 100000
#define CC 128
#define KK 32
#define BG 16
#define EPSF 1e-9f

#define NTILES 1563   // ceil(NN/64)

// d_out float layout: out[16][32][128] | s[100000][32] | mu[16][32][2] | losses[9]
#define S_OFF 65536
#define MU_OFF 3265536
#define LOSS_OFF 3266560

// ws float layout (stats), then W fragment buffers at byte offsets
#define WS_ENT 0
#define WS_SB_S 16
#define WS_SB_PX 528
#define WS_SB_PY 1040
#define WS_SB_SQ 1552
#define WS_TOTAL 2064

#define W1B_OFF_BYTES 16384
#define W2B_OFF_BYTES (16384 + 32768)

typedef __attribute__((ext_vector_type(8))) _Float16 half8;
typedef __attribute__((ext_vector_type(4))) _Float16 half4v;
typedef __attribute__((ext_vector_type(4))) float float4v;

#define MFMAH(a, b, c) __builtin_amdgcn_mfma_f32_16x16x32_f16((a), (b), (c), 0, 0, 0)

// ---------------- prep: W1/W2 -> fp16 B-fragment layout ----------------
// B-frag for mfma_16x16x32: lane l holds B[k'][n], k' = ks*32 + (l>>4)*8 + j, n = nt*16 + (l&15)
__global__ __launch_bounds__(256) void k_prep(const float* __restrict__ W1,
                                              const float* __restrict__ W2,
                                              _Float16* __restrict__ wW1,
                                              _Float16* __restrict__ wW2) {
    int tid = blockIdx.x * 256 + threadIdx.x;
    if (tid < 8 * 4 * 64) {                       // W1: nt(8), ks(4), lane(64)
        int l = tid & 63, ks = (tid >> 6) & 3, nt = tid >> 8;
        int n = nt * 16 + (l & 15);
        int cb = ks * 32 + (l >> 4) * 8;
        half8 H;
#pragma unroll
        for (int j = 0; j < 8; ++j) H[j] = (_Float16)W1[(size_t)(cb + j) * CC + n];
        ((half8*)wW1)[(nt * 4 + ks) * 64 + l] = H;
    } else if (tid < 2048 + 512) {                // W2: nt(2), ks(4), lane(64)
        int t2 = tid - 2048;
        int l = t2 & 63, ks = (t2 >> 6) & 3, nt = t2 >> 8;
        int n = nt * 16 + (l & 15);
        int cb = ks * 32 + (l >> 4) * 8;
        half8 H;
#pragma unroll
        for (int j = 0; j < 8; ++j) H[j] = (_Float16)W2[(size_t)(cb + j) * KK + n];
        ((half8*)wW2)[(nt * 4 + ks) * 64 + l] = H;
    }
}

// ---------------- fused single-tile: MLP (fp16 MFMA) + gumbel softmax + stats + pooling ----------------
__global__ __launch_bounds__(256, 4) void k_assign(
    const float* __restrict__ x, const int* __restrict__ batch,
    const float* __restrict__ pos, const float* __restrict__ gum,
    const float* __restrict__ b1, const float* __restrict__ b2,
    const float* __restrict__ scaling, const float* __restrict__ amask,
    const _Float16* __restrict__ wW1, const _Float16* __restrict__ wW2,
    float* __restrict__ dout, float* __restrict__ ws)
{
    __shared__ _Float16 xh[64][136];   // x fp16, h after S3; dead after GEMM2 -> aliased as sbuf
    __shared__ _Float16 st[32][72];    // s^T fp16 (pooling A + stats)
    __shared__ float lpx[64], lpy[64], lpsq[64];
    __shared__ int lbat[64];
    float* sbuf = (float*)&xh[0][0];   // [4 stats][8 ch][32 k] floats = 4 KB, reuse after GEMM2

    const int t = threadIdx.x;
    // bijective XCD-chunked swizzle: XCD c owns a contiguous tile range (~2 graphs)
    const int orig = blockIdx.x;
    const int qq = NTILES >> 3, rr8 = NTILES & 7;   // 195, 3
    const int xcd = orig & 7, sidx = orig >> 3;
    const int tile = (xcd < rr8 ? xcd * (qq + 1) : rr8 * (qq + 1) + (xcd - rr8) * qq) + sidx;
    const int n0 = tile * 64;

    const int l = t & 63;
    const int wv = __builtin_amdgcn_readfirstlane(t >> 6);
    const int li = l & 15;
    const int g16 = l >> 4;
    const int cc4 = (t & 31) * 4;
    const int nb = t >> 5;
    const int ca  = (2 * wv) * 16 + li;     // pooling c-col 0
    const int cb2 = (2 * wv + 1) * 16 + li; // pooling c-col 1
    const int sk = t & 31, sch = t >> 5;    // stats mapping

    const float scal = scaling[0];
    const float b2v0 = b2[li], b2v1 = b2[16 + li];
    const float am0 = amask[li], am1 = amask[16 + li];
    const float bv0 = b1[(2 * wv) * 16 + li];
    const float bv1 = b1[(2 * wv + 1) * 16 + li];

    // ---- stage x -> fp16 LDS (coalesced float4) ----
#pragma unroll
    for (int r = 0; r < 8; ++r) {
        int n = r * 8 + nb;
        int gn = n0 + n;
        float4 v = make_float4(0.f, 0.f, 0.f, 0.f);
        if (gn < NN) v = *(const float4*)(x + (size_t)gn * CC + cc4);
        *(half4v*)&xh[n][cc4] =
            (half4v){(_Float16)v.x, (_Float16)v.y, (_Float16)v.z, (_Float16)v.w};
    }
    if (t < 64) {
        int gn = n0 + t;
        float px = 0.f, py = 0.f; int bb = BG - 1;
        if (gn < NN) { px = pos[gn * 2]; py = pos[gn * 2 + 1]; bb = batch[gn]; }
        lpx[t] = px; lpy[t] = py; lpsq[t] = px * px + py * py; lbat[t] = bb;
    }

    // ---- issue gumbel loads early (consumed in softmax; hidden under GEMM1/2) ----
    float gu[8];
#pragma unroll
    for (int r2 = 0; r2 < 4; ++r2) {
        int gn = n0 + wv * 16 + g16 * 4 + r2;
        bool valid = gn < NN;
        gu[r2 * 2]     = valid ? gum[(size_t)gn * KK + li]      : 0.5f;
        gu[r2 * 2 + 1] = valid ? gum[(size_t)gn * KK + 16 + li] : 0.5f;
    }
    __syncthreads();   // S1: x tile + meta staged

    // ---- pooling B-frags: x column-slices from xh into regs (before h overwrite) ----
    half8 vx00, vx01, vx10, vx11;   // [ksl][col]
#pragma unroll
    for (int j = 0; j < 8; ++j) {
        vx00[j] = xh[     g16 * 8 + j][ca];
        vx01[j] = xh[     g16 * 8 + j][cb2];
        vx10[j] = xh[32 + g16 * 8 + j][ca];
        vx11[j] = xh[32 + g16 * 8 + j][cb2];
    }

    // ---- GEMM1: h = x @ W1 (fp16) ----
    float4v acc[4][2];
#pragma unroll
    for (int mt = 0; mt < 4; ++mt) {
        acc[mt][0] = (float4v){0.f, 0.f, 0.f, 0.f};
        acc[mt][1] = (float4v){0.f, 0.f, 0.f, 0.f};
    }
    const half8* W1B = (const half8*)wW1;
#pragma unroll
    for (int ks = 0; ks < 4; ++ks) {
        half8 bh0 = W1B[((2 * wv    ) * 4 + ks) * 64 + l];
        half8 bh1 = W1B[((2 * wv + 1) * 4 + ks) * 64 + l];
#pragma unroll
        for (int mt = 0; mt < 4; ++mt) {
            half8 ah = *(const half8*)&xh[mt * 16 + li][ks * 32 + g16 * 8];
            acc[mt][0] = MFMAH(ah, bh0, acc[mt][0]);
            acc[mt][1] = MFMAH(ah, bh1, acc[mt][1]);
        }
    }
    __syncthreads();   // S2: all x reads (GEMM1 + vx frags) done

    // ---- h = relu(acc + b1) -> xh (fp16) ----
#pragma unroll
    for (int mt = 0; mt < 4; ++mt) {
#pragma unroll
        for (int r2 = 0; r2 < 4; ++r2) {
            int row = mt * 16 + g16 * 4 + r2;
            xh[row][(2 * wv) * 16 + li]     = (_Float16)fmaxf(acc[mt][0][r2] + bv0, 0.f);
            xh[row][(2 * wv + 1) * 16 + li] = (_Float16)fmaxf(acc[mt][1][r2] + bv1, 0.f);
        }
    }
    __syncthreads();   // S3: h ready

    // ---- GEMM2: logits = h @ W2 ----
    float4v acc2[2];
    acc2[0] = (float4v){0.f, 0.f, 0.f, 0.f};
    acc2[1] = (float4v){0.f, 0.f, 0.f, 0.f};
    const half8* W2B = (const half8*)wW2;
#pragma unroll
    for (int ks = 0; ks < 4; ++ks) {
        half8 ah = *(const half8*)&xh[wv * 16 + li][ks * 32 + g16 * 8];
        acc2[0] = MFMAH(ah, W2B[(0 * 4 + ks) * 64 + l], acc2[0]);
        acc2[1] = MFMAH(ah, W2B[(1 * 4 + ks) * 64 + l], acc2[1]);
    }

    // ---- softmax in registers; lane owns k={li,16+li} of rows g16*4+r2, m-tile wv ----
    float ep_acc = 0.f;
#pragma unroll
    for (int r2 = 0; r2 < 4; ++r2) {
        int m = wv * 16 + g16 * 4 + r2;
        int gn = n0 + m;
        bool valid = gn < NN;
        float lg0 = (acc2[0][r2] + b2v0) * scal; if (am0 == 0.f) lg0 = -1e9f;
        float lg1 = (acc2[1][r2] + b2v1) * scal; if (am1 == 0.f) lg1 = -1e9f;
        float z0 = lg0 - __logf(-__logf(gu[r2 * 2] + EPSF) + EPSF);
        float z1 = lg1 - __logf(-__logf(gu[r2 * 2 + 1] + EPSF) + EPSF);
        float mx = fmaxf(z0, z1);
        mx = fmaxf(mx, __shfl_xor(mx, 1));
        mx = fmaxf(mx, __shfl_xor(mx, 2));
        mx = fmaxf(mx, __shfl_xor(mx, 4));
        mx = fmaxf(mx, __shfl_xor(mx, 8));
        float e0 = __expf(z0 - mx), e1 = __expf(z1 - mx);
        float sm = e0 + e1;
        sm += __shfl_xor(sm, 1);
        sm += __shfl_xor(sm, 2);
        sm += __shfl_xor(sm, 4);
        sm += __shfl_xor(sm, 8);
        float inv = 1.f / sm;
        float s0 = e0 * inv, s1 = e1 * inv;
        if (!valid) { s0 = 0.f; s1 = 0.f; }
        else {
            dout[S_OFF + (size_t)gn * KK + li] = s0;
            dout[S_OFF + (size_t)gn * KK + 16 + li] = s1;
        }
        st[li][m] = (_Float16)s0;
        st[16 + li][m] = (_Float16)s1;
        ep_acc += s0 * __logf(s0 + EPSF) + s1 * __logf(s1 + EPSF);
    }
    __syncthreads();   // S4: st ready; xh dead from here (sbuf aliases it)

    // ---- segment geometry (block-uniform) ----
    const int b0 = lbat[0], b63 = lbat[63];
    int cut = 64;
    if (b0 != b63) {
        for (int i = 1; i < 64; ++i) { if (lbat[i] != b0) { cut = i; break; } }
    }
    const int nseg = (b0 == b63) ? 1 : 2;

    // ---- stats: per-thread partials -> LDS -> 128 atomics per segment ----
#pragma unroll 1
    for (int sg = 0; sg < nseg; ++sg) {
        const int lo = sg ? cut : 0;
        const int hi = sg ? 64 : cut;
        const int bb = sg ? b63 : b0;
        float prs = 0.f, ppx = 0.f, ppy = 0.f, psq = 0.f;
#pragma unroll
        for (int r = 0; r < 8; ++r) {
            int n = sch * 8 + r;
            if (n >= lo && n < hi) {
                float sv = (float)st[sk][n];
                prs += sv; ppx += sv * lpx[n]; ppy += sv * lpy[n]; psq += sv * lpsq[n];
            }
        }
        if (sg) __syncthreads();   // prior segment's reduce reads done
        sbuf[(0 * 8 + sch) * 32 + sk] = prs;
        sbuf[(1 * 8 + sch) * 32 + sk] = ppx;
        sbuf[(2 * 8 + sch) * 32 + sk] = ppy;
        sbuf[(3 * 8 + sch) * 32 + sk] = psq;
        __syncthreads();
        if (t < 128) {
            int stat = t >> 5, k = t & 31;
            float a = 0.f;
#pragma unroll
            for (int c = 0; c < 8; ++c) a += sbuf[(stat * 8 + c) * 32 + k];
            int off = (stat == 0) ? WS_SB_S : (stat == 1) ? WS_SB_PX
                    : (stat == 2) ? WS_SB_PY : WS_SB_SQ;
            atomicAdd(ws + off + bb * KK + k, a);
        }
    }

    // ---- pooling: out[b] += s^T x via MFMA, flush per segment ----
    float4v p00 = {0.f, 0.f, 0.f, 0.f}, p01 = p00, p10 = p00, p11 = p00;
    auto pool_flush = [&](int bb) {
        float* ob = dout + (size_t)bb * KK * CC;
#pragma unroll
        for (int r2 = 0; r2 < 4; ++r2) {
            int k0r = g16 * 4 + r2;
            atomicAdd(ob + k0r * CC + ca, p00[r2]);
            atomicAdd(ob + k0r * CC + cb2, p01[r2]);
            atomicAdd(ob + (16 + k0r) * CC + ca, p10[r2]);
            atomicAdd(ob + (16 + k0r) * CC + cb2, p11[r2]);
        }
        p00 = (float4v){0.f, 0.f, 0.f, 0.f}; p01 = p00; p10 = p00; p11 = p00;
    };
    if (b0 == b63) {
#pragma unroll
        for (int ksl = 0; ksl < 2; ++ksl) {
            half8 a0 = *(const half8*)&st[li][ksl * 32 + g16 * 8];
            half8 a1 = *(const half8*)&st[16 + li][ksl * 32 + g16 * 8];
            half8 v0 = ksl ? vx10 : vx00;
            half8 v1 = ksl ? vx11 : vx01;
            p00 = MFMAH(a0, v0, p00);
            p01 = MFMAH(a0, v1, p01);
            p10 = MFMAH(a1, v0, p10);
            p11 = MFMAH(a1, v1, p11);
        }
        pool_flush(b0);
    } else {
#pragma unroll 1
        for (int pass = 0; pass < 2; ++pass) {
            int lo = pass ? cut : 0;
            int hi = pass ? 64 : cut;
            int bb = pass ? b63 : b0;
#pragma unroll
            for (int ksl = 0; ksl < 2; ++ksl) {
                half8 a0, a1;
#pragma unroll
                for (int j = 0; j < 8; ++j) {
                    int i = ksl * 32 + g16 * 8 + j;
                    bool in = (i >= lo) && (i < hi);
                    a0[j] = in ? st[li][i] : (_Float16)0.f;
                    a1[j] = in ? st[16 + li][i] : (_Float16)0.f;
                }
                half8 v0 = ksl ? vx10 : vx00;
                half8 v1 = ksl ? vx11 : vx01;
                p00 = MFMAH(a0, v0, p00);
                p01 = MFMAH(a0, v1, p01);
                p10 = MFMAH(a1, v0, p10);
                p11 = MFMAH(a1, v1, p11);
            }
            pool_flush(bb);
        }
    }

    // ---- entropy: wave reduce, 1 atomic/wave ----
    ep_acc += __shfl_xor(ep_acc, 1);
    ep_acc += __shfl_xor(ep_acc, 2);
    ep_acc += __shfl_xor(ep_acc, 4);
    ep_acc += __shfl_xor(ep_acc, 8);
    ep_acc += __shfl_xor(ep_acc, 16);
    ep_acc += __shfl_xor(ep_acc, 32);
    if (l == 0) atomicAdd(ws + WS_ENT, ep_acc);
}

// ---------------- finalize losses + centroids ----------------
__global__ __launch_bounds__(256) void k_final(
    const float* __restrict__ ws, const float* __restrict__ amask,
    float* __restrict__ dout)
{
    __shared__ float avg[32], csum[32], cpx[32], cpy[32], csq[32];
    __shared__ float lmu[16][32][2];
    __shared__ float red[4];
    const int t = threadIdx.x;
    if (t < 32) {
        float a = 0.f, px = 0.f, py = 0.f, sq = 0.f;
        for (int b = 0; b < BG; ++b) {
            a  += ws[WS_SB_S  + b * KK + t];
            px += ws[WS_SB_PX + b * KK + t];
            py += ws[WS_SB_PY + b * KK + t];
            sq += ws[WS_SB_SQ + b * KK + t];
        }
        csum[t] = a; cpx[t] = px; cpy[t] = py; csq[t] = sq;
        avg[t] = a / (float)NN;
    }
    for (int idx = t; idx < BG * KK; idx += 256) {
        float den = ws[WS_SB_S + idx] + EPSF;
        float mx = ws[WS_SB_PX + idx] / den;
        float my = ws[WS_SB_PY + idx] / den;
        int b = idx >> 5, k = idx & 31;
        lmu[b][k][0] = mx; lmu[b][k][1] = my;
        dout[MU_OFF + idx * 2] = mx;
        dout[MU_OFF + idx * 2 + 1] = my;
    }
    __syncthreads();
    float sep = 0.f;
    for (int idx = t; idx < BG * KK * KK; idx += 256) {
        int b = idx >> 10, k1 = (idx >> 5) & 31, k2 = idx & 31;
        if (k1 != k2) {
            float dx = lmu[b][k1][0] - lmu[b][k2][0];
            float dy = lmu[b][k1][1] - lmu[b][k2][1];
            sep += 1.f / (dx * dx + dy * dy + 1.f);
        }
    }
    for (int off = 32; off; off >>= 1) sep += __shfl_down(sep, off);
    if ((t & 63) == 0) red[t >> 6] = sep;
    __syncthreads();
    if (t == 0) {
        float sept = red[0] + red[1] + red[2] + red[3];
        float separation = sept / ((float)(KK * (KK - 1)) + EPSF);
        float entropy = -ws[WS_ENT] / (float)NN;
        float diversity = 0.f, pruning = 0.f, msum = 0.f, entavg = 0.f, bal = 0.f, mxa = 0.f, spatial = 0.f;
        const float up = 1.f / (float)KK;
        for (int k = 0; k < KK; ++k) {
            float a = avg[k];
            diversity += up * logf(up / (a + EPSF));
            float mk = amask[k];
            pruning += fabsf(a * (1.f - mk));
            msum += mk;
            entavg -= a * logf(a + EPSF);
            bal += a * logf(a * (float)KK + EPSF);
            mxa = fmaxf(mxa, a);
            float den = csum[k] + EPSF;
            float mux = cpx[k] / den, muy = cpy[k] / den;
            spatial += csq[k] / den - (mux * mux + muy * muy);
        }
        pruning *= up;
        spatial *= up;
        const float lk = logf((float)KK);
        float collapse = ((lk - entavg) / lk + fmaxf(mxa - 2.f / (float)KK, 0.f)) * 2.0f;
        float sparsity = (msum / (float)KK) * 0.01f;
        dout[LOSS_OFF + 0] = entropy;
        dout[LOSS_OFF + 1] = diversity;
        dout[LOSS_OFF + 2] = spatial;
        dout[LOSS_OFF + 3] = pruning;
        dout[LOSS_OFF + 4] = sparsity;
        dout[LOSS_OFF + 5] = 0.f;
        dout[LOSS_OFF + 6] = collapse;
        dout[LOSS_OFF + 7] = bal;
        dout[LOSS_OFF + 8] = separation;
    }
}

extern "C" void kernel_launch(void* const* d_in, const int* in_sizes, int n_in,
                              void* d_out, int out_size, void* d_ws, size_t ws_size,
                              hipStream_t stream) {
    const float* x     = (const float*)d_in[0];
    const int*   batch = (const int*)d_in[1];
    const float* pos   = (const float*)d_in[2];
    const float* gum   = (const float*)d_in[3];
    const float* W1    = (const float*)d_in[4];
    const float* b1    = (const float*)d_in[5];
    const float* W2    = (const float*)d_in[6];
    const float* b2    = (const float*)d_in[7];
    const float* scal  = (const float*)d_in[8];
    const float* amask = (const float*)d_in[9];
    float* dout = (float*)d_out;
    float* ws   = (float*)d_ws;
    _Float16* wW1 = (_Float16*)((char*)d_ws + W1B_OFF_BYTES);
    _Float16* wW2 = (_Float16*)((char*)d_ws + W2B_OFF_BYTES);

    hipMemsetAsync(dout, 0, S_OFF * sizeof(float), stream);   // pooled-out region
    hipMemsetAsync(ws, 0, WS_TOTAL * sizeof(float), stream);  // stats accumulators

    k_prep<<<10, 256, 0, stream>>>(W1, W2, wW1, wW2);
    k_assign<<<NTILES, 256, 0, stream>>>(x, batch, pos, gum, b1, b2,
                                         scal, amask, wW1, wW2, dout, ws);
    k_final<<<1, 256, 0, stream>>>(ws, amask, dout);
}

// Round 8
// 92.698 us; speedup vs baseline: 3.0267x; 1.5042x over previous
//
#include <hip/hip_runtime.h>
#include <math.h>

#define NN 100000
#define CC 128
#define KK 32
#define BG 16
#define EPSF 1e-9f

#define NTILES 1563   // ceil(NN/64)

// d_out float layout: out[16][32][128] | s[100000][32] | mu[16][32][2] | losses[9]
#define S_OFF 65536
#define MU_OFF 3265536
#define LOSS_OFF 3266560

// ws float layout (stats), entropy partials, then W fragment buffers at byte offsets
#define WS_SB_S 16
#define WS_SB_PX 528
#define WS_SB_PY 1040
#define WS_SB_SQ 1552
#define WS_TOTAL 2064
#define WS_ENTARR 2064        // [NTILES] per-block entropy partials (plain stores)

#define W1B_OFF_BYTES 16384
#define W2B_OFF_BYTES (16384 + 32768)

typedef __attribute__((ext_vector_type(8))) _Float16 half8;
typedef __attribute__((ext_vector_type(4))) _Float16 half4v;
typedef __attribute__((ext_vector_type(4))) float float4v;

#define MFMAH(a, b, c) __builtin_amdgcn_mfma_f32_16x16x32_f16((a), (b), (c), 0, 0, 0)

// ---------------- prep: W1/W2 -> fp16 B-fragment layout ----------------
// B-frag for mfma_16x16x32: lane l holds B[k'][n], k' = ks*32 + (l>>4)*8 + j, n = nt*16 + (l&15)
__global__ __launch_bounds__(256) void k_prep(const float* __restrict__ W1,
                                              const float* __restrict__ W2,
                                              _Float16* __restrict__ wW1,
                                              _Float16* __restrict__ wW2) {
    int tid = blockIdx.x * 256 + threadIdx.x;
    if (tid < 8 * 4 * 64) {                       // W1: nt(8), ks(4), lane(64)
        int l = tid & 63, ks = (tid >> 6) & 3, nt = tid >> 8;
        int n = nt * 16 + (l & 15);
        int cb = ks * 32 + (l >> 4) * 8;
        half8 H;
#pragma unroll
        for (int j = 0; j < 8; ++j) H[j] = (_Float16)W1[(size_t)(cb + j) * CC + n];
        ((half8*)wW1)[(nt * 4 + ks) * 64 + l] = H;
    } else if (tid < 2048 + 512) {                // W2: nt(2), ks(4), lane(64)
        int t2 = tid - 2048;
        int l = t2 & 63, ks = (t2 >> 6) & 3, nt = t2 >> 8;
        int n = nt * 16 + (l & 15);
        int cb = ks * 32 + (l >> 4) * 8;
        half8 H;
#pragma unroll
        for (int j = 0; j < 8; ++j) H[j] = (_Float16)W2[(size_t)(cb + j) * KK + n];
        ((half8*)wW2)[(nt * 4 + ks) * 64 + l] = H;
    }
}

// ---------------- fused single-tile: MLP (fp16 MFMA) + gumbel softmax + stats + pooling ----------------
__global__ __launch_bounds__(256, 4) void k_assign(
    const float* __restrict__ x, const int* __restrict__ batch,
    const float* __restrict__ pos, const float* __restrict__ gum,
    const float* __restrict__ b1, const float* __restrict__ b2,
    const float* __restrict__ scaling, const float* __restrict__ amask,
    const _Float16* __restrict__ wW1, const _Float16* __restrict__ wW2,
    float* __restrict__ dout, float* __restrict__ ws)
{
    __shared__ _Float16 xh[64][136];   // x fp16, h after S3; dead after GEMM2 -> aliased as sbuf
    __shared__ _Float16 st[32][72];    // s^T fp16 (pooling A + stats)
    __shared__ float lpx[64], lpy[64], lpsq[64];
    __shared__ int lbat[64];
    float* sbuf = (float*)&xh[0][0];   // [4 stats][8 ch][32 k] + [4] entropy partials

    const int t = threadIdx.x;
    // bijective XCD-chunked swizzle: XCD c owns a contiguous tile range (~2 graphs)
    const int orig = blockIdx.x;
    const int qq = NTILES >> 3, rr8 = NTILES & 7;   // 195, 3
    const int xcd = orig & 7, sidx = orig >> 3;
    const int tile = (xcd < rr8 ? xcd * (qq + 1) : rr8 * (qq + 1) + (xcd - rr8) * qq) + sidx;
    const int n0 = tile * 64;

    const int l = t & 63;
    const int wv = __builtin_amdgcn_readfirstlane(t >> 6);
    const int li = l & 15;
    const int g16 = l >> 4;
    const int cc4 = (t & 31) * 4;
    const int nb = t >> 5;
    const int ca  = (2 * wv) * 16 + li;     // pooling c-col 0
    const int cb2 = (2 * wv + 1) * 16 + li; // pooling c-col 1
    const int sk = t & 31, sch = t >> 5;    // stats mapping

    const float scal = scaling[0];
    const float b2v0 = b2[li], b2v1 = b2[16 + li];
    const float am0 = amask[li], am1 = amask[16 + li];
    const float bv0 = b1[(2 * wv) * 16 + li];
    const float bv1 = b1[(2 * wv + 1) * 16 + li];

    // ---- stage x -> fp16 LDS (coalesced float4) ----
#pragma unroll
    for (int r = 0; r < 8; ++r) {
        int n = r * 8 + nb;
        int gn = n0 + n;
        float4 v = make_float4(0.f, 0.f, 0.f, 0.f);
        if (gn < NN) v = *(const float4*)(x + (size_t)gn * CC + cc4);
        *(half4v*)&xh[n][cc4] =
            (half4v){(_Float16)v.x, (_Float16)v.y, (_Float16)v.z, (_Float16)v.w};
    }
    if (t < 64) {
        int gn = n0 + t;
        float px = 0.f, py = 0.f; int bb = BG - 1;
        if (gn < NN) { px = pos[gn * 2]; py = pos[gn * 2 + 1]; bb = batch[gn]; }
        lpx[t] = px; lpy[t] = py; lpsq[t] = px * px + py * py; lbat[t] = bb;
    }

    // ---- issue gumbel loads early (consumed in softmax; hidden under GEMM1/2) ----
    float gu[8];
#pragma unroll
    for (int r2 = 0; r2 < 4; ++r2) {
        int gn = n0 + wv * 16 + g16 * 4 + r2;
        bool valid = gn < NN;
        gu[r2 * 2]     = valid ? gum[(size_t)gn * KK + li]      : 0.5f;
        gu[r2 * 2 + 1] = valid ? gum[(size_t)gn * KK + 16 + li] : 0.5f;
    }
    __syncthreads();   // S1: x tile + meta staged

    // ---- pooling B-frags: x column-slices from xh into regs (before h overwrite) ----
    half8 vx00, vx01, vx10, vx11;   // [ksl][col]
#pragma unroll
    for (int j = 0; j < 8; ++j) {
        vx00[j] = xh[     g16 * 8 + j][ca];
        vx01[j] = xh[     g16 * 8 + j][cb2];
        vx10[j] = xh[32 + g16 * 8 + j][ca];
        vx11[j] = xh[32 + g16 * 8 + j][cb2];
    }

    // ---- GEMM1: h = x @ W1 (fp16) ----
    float4v acc[4][2];
#pragma unroll
    for (int mt = 0; mt < 4; ++mt) {
        acc[mt][0] = (float4v){0.f, 0.f, 0.f, 0.f};
        acc[mt][1] = (float4v){0.f, 0.f, 0.f, 0.f};
    }
    const half8* W1B = (const half8*)wW1;
#pragma unroll
    for (int ks = 0; ks < 4; ++ks) {
        half8 bh0 = W1B[((2 * wv    ) * 4 + ks) * 64 + l];
        half8 bh1 = W1B[((2 * wv + 1) * 4 + ks) * 64 + l];
#pragma unroll
        for (int mt = 0; mt < 4; ++mt) {
            half8 ah = *(const half8*)&xh[mt * 16 + li][ks * 32 + g16 * 8];
            acc[mt][0] = MFMAH(ah, bh0, acc[mt][0]);
            acc[mt][1] = MFMAH(ah, bh1, acc[mt][1]);
        }
    }
    __syncthreads();   // S2: all x reads (GEMM1 + vx frags) done

    // ---- h = relu(acc + b1) -> xh (fp16) ----
#pragma unroll
    for (int mt = 0; mt < 4; ++mt) {
#pragma unroll
        for (int r2 = 0; r2 < 4; ++r2) {
            int row = mt * 16 + g16 * 4 + r2;
            xh[row][(2 * wv) * 16 + li]     = (_Float16)fmaxf(acc[mt][0][r2] + bv0, 0.f);
            xh[row][(2 * wv + 1) * 16 + li] = (_Float16)fmaxf(acc[mt][1][r2] + bv1, 0.f);
        }
    }
    __syncthreads();   // S3: h ready

    // ---- GEMM2: logits = h @ W2 ----
    float4v acc2[2];
    acc2[0] = (float4v){0.f, 0.f, 0.f, 0.f};
    acc2[1] = (float4v){0.f, 0.f, 0.f, 0.f};
    const half8* W2B = (const half8*)wW2;
#pragma unroll
    for (int ks = 0; ks < 4; ++ks) {
        half8 ah = *(const half8*)&xh[wv * 16 + li][ks * 32 + g16 * 8];
        acc2[0] = MFMAH(ah, W2B[(0 * 4 + ks) * 64 + l], acc2[0]);
        acc2[1] = MFMAH(ah, W2B[(1 * 4 + ks) * 64 + l], acc2[1]);
    }

    // ---- softmax in registers; lane owns k={li,16+li} of rows g16*4+r2, m-tile wv ----
    float ep_acc = 0.f;
#pragma unroll
    for (int r2 = 0; r2 < 4; ++r2) {
        int m = wv * 16 + g16 * 4 + r2;
        int gn = n0 + m;
        bool valid = gn < NN;
        float lg0 = (acc2[0][r2] + b2v0) * scal; if (am0 == 0.f) lg0 = -1e9f;
        float lg1 = (acc2[1][r2] + b2v1) * scal; if (am1 == 0.f) lg1 = -1e9f;
        float z0 = lg0 - __logf(-__logf(gu[r2 * 2] + EPSF) + EPSF);
        float z1 = lg1 - __logf(-__logf(gu[r2 * 2 + 1] + EPSF) + EPSF);
        float mx = fmaxf(z0, z1);
        mx = fmaxf(mx, __shfl_xor(mx, 1));
        mx = fmaxf(mx, __shfl_xor(mx, 2));
        mx = fmaxf(mx, __shfl_xor(mx, 4));
        mx = fmaxf(mx, __shfl_xor(mx, 8));
        float e0 = __expf(z0 - mx), e1 = __expf(z1 - mx);
        float sm = e0 + e1;
        sm += __shfl_xor(sm, 1);
        sm += __shfl_xor(sm, 2);
        sm += __shfl_xor(sm, 4);
        sm += __shfl_xor(sm, 8);
        float inv = 1.f / sm;
        float s0 = e0 * inv, s1 = e1 * inv;
        if (!valid) { s0 = 0.f; s1 = 0.f; }
        else {
            dout[S_OFF + (size_t)gn * KK + li] = s0;
            dout[S_OFF + (size_t)gn * KK + 16 + li] = s1;
        }
        st[li][m] = (_Float16)s0;
        st[16 + li][m] = (_Float16)s1;
        ep_acc += s0 * __logf(s0 + EPSF) + s1 * __logf(s1 + EPSF);
    }
    __syncthreads();   // S4: st ready; xh dead from here (sbuf aliases it)

    // ---- entropy: wave-reduce -> LDS partials (no global atomic) ----
    ep_acc += __shfl_xor(ep_acc, 1);
    ep_acc += __shfl_xor(ep_acc, 2);
    ep_acc += __shfl_xor(ep_acc, 4);
    ep_acc += __shfl_xor(ep_acc, 8);
    ep_acc += __shfl_xor(ep_acc, 16);
    ep_acc += __shfl_xor(ep_acc, 32);
    if (l == 0) sbuf[1024 + wv] = ep_acc;

    // ---- segment geometry (block-uniform) ----
    const int b0 = lbat[0], b63 = lbat[63];
    int cut = 64;
    if (b0 != b63) {
        for (int i = 1; i < 64; ++i) { if (lbat[i] != b0) { cut = i; break; } }
    }
    const int nseg = (b0 == b63) ? 1 : 2;

    // ---- stats: per-thread partials -> LDS -> 128 atomics per segment ----
#pragma unroll 1
    for (int sg = 0; sg < nseg; ++sg) {
        const int lo = sg ? cut : 0;
        const int hi = sg ? 64 : cut;
        const int bb = sg ? b63 : b0;
        float prs = 0.f, ppx = 0.f, ppy = 0.f, psq = 0.f;
#pragma unroll
        for (int r = 0; r < 8; ++r) {
            int n = sch * 8 + r;
            if (n >= lo && n < hi) {
                float sv = (float)st[sk][n];
                prs += sv; ppx += sv * lpx[n]; ppy += sv * lpy[n]; psq += sv * lpsq[n];
            }
        }
        if (sg) __syncthreads();   // prior segment's reduce reads done
        sbuf[(0 * 8 + sch) * 32 + sk] = prs;
        sbuf[(1 * 8 + sch) * 32 + sk] = ppx;
        sbuf[(2 * 8 + sch) * 32 + sk] = ppy;
        sbuf[(3 * 8 + sch) * 32 + sk] = psq;
        __syncthreads();
        if (t < 128) {
            int stat = t >> 5, k = t & 31;
            float a = 0.f;
#pragma unroll
            for (int c = 0; c < 8; ++c) a += sbuf[(stat * 8 + c) * 32 + k];
            int off = (stat == 0) ? WS_SB_S : (stat == 1) ? WS_SB_PX
                    : (stat == 2) ? WS_SB_PY : WS_SB_SQ;
            atomicAdd(ws + off + bb * KK + k, a);
        }
    }

    // ---- entropy partial: one plain store per block (slots all overwritten every launch) ----
    if (t == 0) {
        ws[WS_ENTARR + orig] = sbuf[1024] + sbuf[1025] + sbuf[1026] + sbuf[1027];
    }

    // ---- pooling: out[b] += s^T x via MFMA, flush per segment ----
    float4v p00 = {0.f, 0.f, 0.f, 0.f}, p01 = p00, p10 = p00, p11 = p00;
    auto pool_flush = [&](int bb) {
        float* ob = dout + (size_t)bb * KK * CC;
#pragma unroll
        for (int r2 = 0; r2 < 4; ++r2) {
            int k0r = g16 * 4 + r2;
            atomicAdd(ob + k0r * CC + ca, p00[r2]);
            atomicAdd(ob + k0r * CC + cb2, p01[r2]);
            atomicAdd(ob + (16 + k0r) * CC + ca, p10[r2]);
            atomicAdd(ob + (16 + k0r) * CC + cb2, p11[r2]);
        }
        p00 = (float4v){0.f, 0.f, 0.f, 0.f}; p01 = p00; p10 = p00; p11 = p00;
    };
    if (b0 == b63) {
#pragma unroll
        for (int ksl = 0; ksl < 2; ++ksl) {
            half8 a0 = *(const half8*)&st[li][ksl * 32 + g16 * 8];
            half8 a1 = *(const half8*)&st[16 + li][ksl * 32 + g16 * 8];
            half8 v0 = ksl ? vx10 : vx00;
            half8 v1 = ksl ? vx11 : vx01;
            p00 = MFMAH(a0, v0, p00);
            p01 = MFMAH(a0, v1, p01);
            p10 = MFMAH(a1, v0, p10);
            p11 = MFMAH(a1, v1, p11);
        }
        pool_flush(b0);
    } else {
#pragma unroll 1
        for (int pass = 0; pass < 2; ++pass) {
            int lo = pass ? cut : 0;
            int hi = pass ? 64 : cut;
            int bb = pass ? b63 : b0;
#pragma unroll
            for (int ksl = 0; ksl < 2; ++ksl) {
                half8 a0, a1;
#pragma unroll
                for (int j = 0; j < 8; ++j) {
                    int i = ksl * 32 + g16 * 8 + j;
                    bool in = (i >= lo) && (i < hi);
                    a0[j] = in ? st[li][i] : (_Float16)0.f;
                    a1[j] = in ? st[16 + li][i] : (_Float16)0.f;
                }
                half8 v0 = ksl ? vx10 : vx00;
                half8 v1 = ksl ? vx11 : vx01;
                p00 = MFMAH(a0, v0, p00);
                p01 = MFMAH(a0, v1, p01);
                p10 = MFMAH(a1, v0, p10);
                p11 = MFMAH(a1, v1, p11);
            }
            pool_flush(bb);
        }
    }
}

// ---------------- finalize losses + centroids ----------------
__global__ __launch_bounds__(256) void k_final(
    const float* __restrict__ ws, const float* __restrict__ amask,
    float* __restrict__ dout)
{
    __shared__ float avg[32], csum[32], cpx[32], cpy[32], csq[32];
    __shared__ float lmu[16][32][2];
    __shared__ float red[4], ered[4];
    const int t = threadIdx.x;

    // ---- entropy: parallel sum of per-block partials ----
    float esum = 0.f;
    for (int i = t; i < NTILES; i += 256) esum += ws[WS_ENTARR + i];
    esum += __shfl_xor(esum, 1);
    esum += __shfl_xor(esum, 2);
    esum += __shfl_xor(esum, 4);
    esum += __shfl_xor(esum, 8);
    esum += __shfl_xor(esum, 16);
    esum += __shfl_xor(esum, 32);
    if ((t & 63) == 0) ered[t >> 6] = esum;

    if (t < 32) {
        float a = 0.f, px = 0.f, py = 0.f, sq = 0.f;
        for (int b = 0; b < BG; ++b) {
            a  += ws[WS_SB_S  + b * KK + t];
            px += ws[WS_SB_PX + b * KK + t];
            py += ws[WS_SB_PY + b * KK + t];
            sq += ws[WS_SB_SQ + b * KK + t];
        }
        csum[t] = a; cpx[t] = px; cpy[t] = py; csq[t] = sq;
        avg[t] = a / (float)NN;
    }
    for (int idx = t; idx < BG * KK; idx += 256) {
        float den = ws[WS_SB_S + idx] + EPSF;
        float mx = ws[WS_SB_PX + idx] / den;
        float my = ws[WS_SB_PY + idx] / den;
        int b = idx >> 5, k = idx & 31;
        lmu[b][k][0] = mx; lmu[b][k][1] = my;
        dout[MU_OFF + idx * 2] = mx;
        dout[MU_OFF + idx * 2 + 1] = my;
    }
    __syncthreads();
    float sep = 0.f;
    for (int idx = t; idx < BG * KK * KK; idx += 256) {
        int b = idx >> 10, k1 = (idx >> 5) & 31, k2 = idx & 31;
        if (k1 != k2) {
            float dx = lmu[b][k1][0] - lmu[b][k2][0];
            float dy = lmu[b][k1][1] - lmu[b][k2][1];
            sep += 1.f / (dx * dx + dy * dy + 1.f);
        }
    }
    for (int off = 32; off; off >>= 1) sep += __shfl_down(sep, off);
    if ((t & 63) == 0) red[t >> 6] = sep;
    __syncthreads();
    if (t == 0) {
        float sept = red[0] + red[1] + red[2] + red[3];
        float separation = sept / ((float)(KK * (KK - 1)) + EPSF);
        float entropy = -(ered[0] + ered[1] + ered[2] + ered[3]) / (float)NN;
        float diversity = 0.f, pruning = 0.f, msum = 0.f, entavg = 0.f, bal = 0.f, mxa = 0.f, spatial = 0.f;
        const float up = 1.f / (float)KK;
        for (int k = 0; k < KK; ++k) {
            float a = avg[k];
            diversity += up * logf(up / (a + EPSF));
            float mk = amask[k];
            pruning += fabsf(a * (1.f - mk));
            msum += mk;
            entavg -= a * logf(a + EPSF);
            bal += a * logf(a * (float)KK + EPSF);
            mxa = fmaxf(mxa, a);
            float den = csum[k] + EPSF;
            float mux = cpx[k] / den, muy = cpy[k] / den;
            spatial += csq[k] / den - (mux * mux + muy * muy);
        }
        pruning *= up;
        spatial *= up;
        const float lk = logf((float)KK);
        float collapse = ((lk - entavg) / lk + fmaxf(mxa - 2.f / (float)KK, 0.f)) * 2.0f;
        float sparsity = (msum / (float)KK) * 0.01f;
        dout[LOSS_OFF + 0] = entropy;
        dout[LOSS_OFF + 1] = diversity;
        dout[LOSS_OFF + 2] = spatial;
        dout[LOSS_OFF + 3] = pruning;
        dout[LOSS_OFF + 4] = sparsity;
        dout[LOSS_OFF + 5] = 0.f;
        dout[LOSS_OFF + 6] = collapse;
        dout[LOSS_OFF + 7] = bal;
        dout[LOSS_OFF + 8] = separation;
    }
}

extern "C" void kernel_launch(void* const* d_in, const int* in_sizes, int n_in,
                              void* d_out, int out_size, void* d_ws, size_t ws_size,
                              hipStream_t stream) {
    const float* x     = (const float*)d_in[0];
    const int*   batch = (const int*)d_in[1];
    const float* pos   = (const float*)d_in[2];
    const float* gum   = (const float*)d_in[3];
    const float* W1    = (const float*)d_in[4];
    const float* b1    = (const float*)d_in[5];
    const float* W2    = (const float*)d_in[6];
    const float* b2    = (const float*)d_in[7];
    const float* scal  = (const float*)d_in[8];
    const float* amask = (const float*)d_in[9];
    float* dout = (float*)d_out;
    float* ws   = (float*)d_ws;
    _Float16* wW1 = (_Float16*)((char*)d_ws + W1B_OFF_BYTES);
    _Float16* wW2 = (_Float16*)((char*)d_ws + W2B_OFF_BYTES);

    hipMemsetAsync(dout, 0, S_OFF * sizeof(float), stream);   // pooled-out region
    hipMemsetAsync(ws, 0, WS_TOTAL * sizeof(float), stream);  // stats accumulators

    k_prep<<<10, 256, 0, stream>>>(W1, W2, wW1, wW2);
    k_assign<<<NTILES, 256, 0, stream>>>(x, batch, pos, gum, b1, b2,
                                         scal, amask, wW1, wW2, dout, ws);
    k_final<<<1, 256, 0, stream>>>(ws, amask, dout);
}